// Round 3
// baseline (337.506 us; speedup 1.0000x reference)
//
#include <hip/hip_runtime.h>
#include <hip/hip_bf16.h>

typedef unsigned short u16;
typedef unsigned int u32;
typedef unsigned char u8;

#define DEV __device__ __forceinline__

DEV float bf2f(u16 u) {
  union { u32 i; float f; } c; c.i = ((u32)u) << 16; return c.f;
}

static constexpr int B = 2, N = 512, D = 128, F = 512;
static constexpr int NROW = B * N;  // 1024
static constexpr float EPS = 1e-5f;
static constexpr float NEG = -1e9f;
static constexpr float SCALE = 0.08838834764831845f;  // 1/sqrt(128)

// ---- normalized-weight region: element offsets (order = d_in[1..28]) ------
static constexpr int NT = 28;
static constexpr int CNT[NT] = {
  256, 128, 32768, 128, 16384, 128, 128, 128, 128, 16384, 128, 16384,
  49152, 384, 49152, 384, 49152, 384, 49152, 384, 384, 384, 384, 384,
  196608, 1536, 196608, 384};
#define OFF_PRE_W   0
#define OFF_PRE_B   256
#define OFF_PROJ_W  384
#define OFF_PROJ_B  33152
#define OFF_OUT_W1  33280
#define OFF_BN_G    49664
#define OFF_BN_B    49792
#define OFF_BN_M    49920
#define OFF_BN_V    50048
#define OFF_OUT_W2  50176
#define OFF_OUT_B2  66560
#define OFF_PE      66688
#define OFF_WQ      83072
#define OFF_BQ      132224
#define OFF_WK      132608
#define OFF_BK      181760
#define OFF_WV      182144
#define OFF_BV      231296
#define OFF_WO      231680
#define OFF_BO      280832
#define OFF_LN1G    281216
#define OFF_LN1B    281600
#define OFF_LN2G    281984
#define OFF_LN2B    282368
#define OFF_FW1     282752
#define OFF_FB1     479360
#define OFF_FW2     480896
#define OFF_FB2     677504
#define W_TOTAL     677888

struct NormArgs { const void* s[NT]; float* d[NT]; int c[NT]; };

// ---------------------------------------------------------------------------
// k_detect: classify input encodings + normalize mask to int 0/1.
// ---------------------------------------------------------------------------
__global__ __launch_bounds__(256) void k_detect(
    const void* __restrict__ bnv, const void* __restrict__ maskp,
    int* __restrict__ flags, int* __restrict__ mbuf)
{
  const int t = threadIdx.x;
  __shared__ int s_nf, s_m4, s_m2;
  if (t == 0) { s_nf = 0; s_m4 = 0; s_m2 = 0; }
  __syncthreads();
  if (t < 64) {
    const u32 w = ((const u32*)bnv)[t];
    if (((w >> 8) & 0xFFu) != 0x3Fu || ((w >> 24) & 0xFFu) != 0x3Fu)
      atomicOr(&s_nf, 1);
  }
  {
    const u32 w = ((const u32*)maskp)[t];
    if (!(w == 0u || w == 1u || w == 0x3F800000u)) atomicOr(&s_m4, 1);
    if (!(w == 0u || w == 1u || w == 0x10000u || w == 0x10001u ||
          w == 0x3F80u || w == 0x3F800000u || w == 0x3F803F80u)) atomicOr(&s_m2, 1);
  }
  __syncthreads();
  const int isb  = s_nf ? 0 : 1;
  const int mode = (!s_m4) ? 4 : ((!s_m2) ? 2 : 1);  // bytes per mask element
  if (t == 0) { flags[0] = isb; flags[1] = mode; }
  #pragma unroll
  for (int k = 0; k < 4; ++k) {
    const int e = k * 256 + t;
    int v;
    if (mode == 4)      v = (((const u32*)maskp)[e] != 0u);
    else if (mode == 2) v = (((const u16*)maskp)[e] != 0);
    else                v = (((const u8*)maskp)[e]  != 0);
    mbuf[e] = v;
  }
}

// ---------------------------------------------------------------------------
// k_norm: convert all float tensors (fp32 or bf16 source) to fp32 in ws.
// ---------------------------------------------------------------------------
__global__ __launch_bounds__(256) void k_norm(NormArgs a, const int* __restrict__ flags) {
  const int ten = blockIdx.y;
  const int n = a.c[ten];
  const int base = blockIdx.x * 1024 + threadIdx.x;
  const int isb = flags[0];
  const float* __restrict__ sf = (const float*)a.s[ten];
  const u16*   __restrict__ sh = (const u16*)a.s[ten];
  float* __restrict__ d = a.d[ten];
  #pragma unroll
  for (int k = 0; k < 4; ++k) {
    const int e = base + k * 256;
    if (e < n) d[e] = isb ? bf2f(sh[e]) : sf[e];
  }
}

// ---------------------------------------------------------------------------
// k_relchain: collapsed pairwise-relation chain + out-MLP + pos embedding.
// ---------------------------------------------------------------------------
__global__ __launch_bounds__(128) void k_relchain(
    const void* __restrict__ relv, const float* __restrict__ W,
    const int* __restrict__ flags, const int* __restrict__ mbuf,
    const int* __restrict__ agent_id, float* __restrict__ xbuf)
{
  const int bi = blockIdx.x;      // b*N + i
  const int b  = bi >> 9;
  const int t  = threadIdx.x;     // 0..127

  __shared__ float red[6];
  __shared__ float pl[D], zl[D], rl[D];

  float s0 = 0.f, s1 = 0.f, cnt = 0.f;
  if (flags[0]) {
    const u32* rel2 = (const u32*)relv;  // packed bf16 pair per (b,i,j)
    #pragma unroll
    for (int jj = 0; jj < 4; ++jj) {
      const int j = jj * 128 + t;
      const float m = (float)mbuf[b * N + j];
      const u32 u = rel2[(size_t)bi * N + j];
      s0 += m * bf2f((u16)(u & 0xFFFFu));
      s1 += m * bf2f((u16)(u >> 16));
      cnt += m;
    }
  } else {
    const float2* relf = (const float2*)relv;
    #pragma unroll
    for (int jj = 0; jj < 4; ++jj) {
      const int j = jj * 128 + t;
      const float m = (float)mbuf[b * N + j];
      const float2 u = relf[(size_t)bi * N + j];
      s0 += m * u.x; s1 += m * u.y; cnt += m;
    }
  }
  #pragma unroll
  for (int o = 32; o > 0; o >>= 1) {
    s0 += __shfl_down(s0, o, 64);
    s1 += __shfl_down(s1, o, 64);
    cnt += __shfl_down(cnt, o, 64);
  }
  if ((t & 63) == 0) {
    const int w = t >> 6;
    red[w * 3 + 0] = s0; red[w * 3 + 1] = s1; red[w * 3 + 2] = cnt;
  }
  __syncthreads();
  const float T0 = red[0] + red[3], T1 = red[1] + red[4], Mtot = red[2] + red[5];
  const int maski = mbuf[bi];

  float pooled = 0.f;
  if (maski)  // maski==1 implies Mtot>=1 (the j==i term)
    pooled = (T0 * W[OFF_PRE_W + t] + T1 * W[OFF_PRE_W + D + t]) / Mtot + W[OFF_PRE_B + t];
  pl[t] = pooled;
  __syncthreads();

  float z = 0.f;
  if (maski) {
    float acc = 0.f;
    for (int e = 0; e < D; ++e)
      acc += pl[e] * (W[OFF_PROJ_W + e * D + t] + W[OFF_PROJ_W + (e + D) * D + t]);
    z = acc + W[OFF_PROJ_B + t];
  }
  zl[t] = z;
  __syncthreads();

  float h = 0.f;
  for (int e = 0; e < D; ++e) h += zl[e] * W[OFF_OUT_W1 + e * D + t];
  const float hb = (h - W[OFF_BN_M + t]) * __frsqrt_rn(W[OFF_BN_V + t] + EPS)
                   * W[OFF_BN_G + t] + W[OFF_BN_B + t];
  rl[t] = fmaxf(hb, 0.f);
  __syncthreads();

  float o2 = 0.f;
  for (int e = 0; e < D; ++e) o2 += rl[e] * W[OFF_OUT_W2 + e * D + t];
  const int aid = agent_id[bi];
  xbuf[(size_t)bi * D + t] = o2 + W[OFF_OUT_B2 + t] + W[OFF_PE + aid * D + t];
}

// ---------------------------------------------------------------------------
// k_qkv (per layer): QKV projections. 4 rows/block, 256 blocks, 128 threads.
// ---------------------------------------------------------------------------
__global__ __launch_bounds__(128) void k_qkv(
    const float* __restrict__ xbuf,
    const float* __restrict__ WQ, const float* __restrict__ bq,
    const float* __restrict__ WK, const float* __restrict__ bk,
    const float* __restrict__ WV, const float* __restrict__ bv,
    float* __restrict__ qb, float* __restrict__ kb, float* __restrict__ vb)
{
  const int t = threadIdx.x;
  const int row0 = blockIdx.x * 4;
  __shared__ float xs[4][D];
  #pragma unroll
  for (int r = 0; r < 4; ++r) xs[r][t] = xbuf[(size_t)(row0 + r) * D + t];
  __syncthreads();

  float q0=0,q1=0,q2=0,q3=0, k0=0,k1=0,k2=0,k3=0, v0=0,v1=0,v2=0,v3=0;
  for (int e = 0; e < D; ++e) {
    const float wqv = WQ[e * D + t];
    const float wkv = WK[e * D + t];
    const float wvv = WV[e * D + t];
    const float x0 = xs[0][e], x1 = xs[1][e], x2 = xs[2][e], x3 = xs[3][e];
    q0 += x0 * wqv; q1 += x1 * wqv; q2 += x2 * wqv; q3 += x3 * wqv;
    k0 += x0 * wkv; k1 += x1 * wkv; k2 += x2 * wkv; k3 += x3 * wkv;
    v0 += x0 * wvv; v1 += x1 * wvv; v2 += x2 * wvv; v3 += x3 * wvv;
  }
  const float bqv = bq[t], bkv = bk[t], bvv = bv[t];
  qb[(size_t)(row0+0)*D+t]=q0+bqv; qb[(size_t)(row0+1)*D+t]=q1+bqv;
  qb[(size_t)(row0+2)*D+t]=q2+bqv; qb[(size_t)(row0+3)*D+t]=q3+bqv;
  kb[(size_t)(row0+0)*D+t]=k0+bkv; kb[(size_t)(row0+1)*D+t]=k1+bkv;
  kb[(size_t)(row0+2)*D+t]=k2+bkv; kb[(size_t)(row0+3)*D+t]=k3+bkv;
  vb[(size_t)(row0+0)*D+t]=v0+bvv; vb[(size_t)(row0+1)*D+t]=v1+bvv;
  vb[(size_t)(row0+2)*D+t]=v2+bvv; vb[(size_t)(row0+3)*D+t]=v3+bvv;
}

// ---------------------------------------------------------------------------
// k_attn (per layer): scores + softmax + AV + out-proj + residual + LN1.
// ---------------------------------------------------------------------------
__global__ __launch_bounds__(128) void k_attn(
    const float* __restrict__ qb, const float* __restrict__ kb, const float* __restrict__ vb,
    const float* __restrict__ WO, const float* __restrict__ bo,
    const float* __restrict__ g1, const float* __restrict__ b1,
    const int* __restrict__ mbuf, float* __restrict__ xbuf)
{
  const int t = threadIdx.x;
  const int row0 = blockIdx.x * 4;
  const int b = row0 >> 9;

  __shared__ float qs[4][D];
  __shared__ float p[4][N];
  __shared__ float os[4][D];
  __shared__ float red[4];

  #pragma unroll
  for (int r = 0; r < 4; ++r) qs[r][t] = qb[(size_t)(row0 + r) * D + t];
  __syncthreads();

  for (int jj = 0; jj < 4; ++jj) {
    const int j = jj * 128 + t;
    const float4* k4 = (const float4*)(kb + (size_t)(b * N + j) * D);
    float a0 = 0, a1 = 0, a2 = 0, a3 = 0;
    for (int e4 = 0; e4 < D / 4; ++e4) {
      const float4 kv = k4[e4];
      const int e = e4 * 4;
      a0 += qs[0][e]*kv.x + qs[0][e+1]*kv.y + qs[0][e+2]*kv.z + qs[0][e+3]*kv.w;
      a1 += qs[1][e]*kv.x + qs[1][e+1]*kv.y + qs[1][e+2]*kv.z + qs[1][e+3]*kv.w;
      a2 += qs[2][e]*kv.x + qs[2][e+1]*kv.y + qs[2][e+2]*kv.z + qs[2][e+3]*kv.w;
      a3 += qs[3][e]*kv.x + qs[3][e+1]*kv.y + qs[3][e+2]*kv.z + qs[3][e+3]*kv.w;
    }
    const float bias = mbuf[b * N + j] ? 0.f : NEG;
    p[0][j] = a0 * SCALE + bias;
    p[1][j] = a1 * SCALE + bias;
    p[2][j] = a2 * SCALE + bias;
    p[3][j] = a3 * SCALE + bias;
  }
  __syncthreads();

  float sden[4];
  #pragma unroll
  for (int r = 0; r < 4; ++r) {
    float lm = -1e30f;
    #pragma unroll
    for (int jj = 0; jj < 4; ++jj) lm = fmaxf(lm, p[r][jj * 128 + t]);
    #pragma unroll
    for (int o = 32; o > 0; o >>= 1) lm = fmaxf(lm, __shfl_down(lm, o, 64));
    if ((t & 63) == 0) red[t >> 6] = lm;
    __syncthreads();
    const float mx = fmaxf(red[0], red[1]);
    __syncthreads();
    float ls = 0.f;
    #pragma unroll
    for (int jj = 0; jj < 4; ++jj) {
      const float ev = __expf(p[r][jj * 128 + t] - mx);
      p[r][jj * 128 + t] = ev;
      ls += ev;
    }
    #pragma unroll
    for (int o = 32; o > 0; o >>= 1) ls += __shfl_down(ls, o, 64);
    if ((t & 63) == 0) red[t >> 6] = ls;
    __syncthreads();
    sden[r] = red[0] + red[1];
    __syncthreads();
  }

  {
    float a0 = 0, a1 = 0, a2 = 0, a3 = 0;
    for (int j = 0; j < N; ++j) {
      const float vv = vb[(size_t)(b * N + j) * D + t];
      a0 += p[0][j] * vv; a1 += p[1][j] * vv; a2 += p[2][j] * vv; a3 += p[3][j] * vv;
    }
    os[0][t] = a0 / sden[0];
    os[1][t] = a1 / sden[1];
    os[2][t] = a2 / sden[2];
    os[3][t] = a3 / sden[3];
  }
  __syncthreads();

  float pr[4] = {0, 0, 0, 0};
  for (int e = 0; e < D; ++e) {
    const float w = WO[e * D + t];
    pr[0] += os[0][e] * w; pr[1] += os[1][e] * w;
    pr[2] += os[2][e] * w; pr[3] += os[3][e] * w;
  }
  const float bov = bo[t], g = g1[t], be = b1[t];
  #pragma unroll
  for (int r = 0; r < 4; ++r) {
    const float tv = pr[r] + bov + xbuf[(size_t)(row0 + r) * D + t];
    float s = tv, sq = tv * tv;
    #pragma unroll
    for (int o = 32; o > 0; o >>= 1) { s += __shfl_down(s, o, 64); sq += __shfl_down(sq, o, 64); }
    if ((t & 63) == 0) { red[(t >> 6) * 2] = s; red[(t >> 6) * 2 + 1] = sq; }
    __syncthreads();
    const float mean = (red[0] + red[2]) * (1.f / 128.f);
    const float var  = (red[1] + red[3]) * (1.f / 128.f) - mean * mean;
    __syncthreads();
    xbuf[(size_t)(row0 + r) * D + t] = (tv - mean) * __frsqrt_rn(var + EPS) * g + be;
  }
}

// ---------------------------------------------------------------------------
// k_ffn (per layer): FFN + residual + LN2; last layer writes fp32 output.
// ---------------------------------------------------------------------------
__global__ __launch_bounds__(128) void k_ffn(
    const float* __restrict__ W1, const float* __restrict__ fb1,
    const float* __restrict__ W2, const float* __restrict__ fb2,
    const float* __restrict__ g2, const float* __restrict__ b2v,
    float* __restrict__ xbuf, float* __restrict__ outp)
{
  const int t = threadIdx.x;
  const int row0 = blockIdx.x * 4;

  __shared__ float xs[4][D];
  __shared__ float hs[4][F];
  __shared__ float red[4];

  #pragma unroll
  for (int r = 0; r < 4; ++r) xs[r][t] = xbuf[(size_t)(row0 + r) * D + t];
  __syncthreads();

  for (int ff = 0; ff < 4; ++ff) {
    const int f = ff * 128 + t;
    float a0 = 0, a1 = 0, a2 = 0, a3 = 0;
    for (int e = 0; e < D; ++e) {
      const float w = W1[e * F + f];
      a0 += xs[0][e] * w; a1 += xs[1][e] * w; a2 += xs[2][e] * w; a3 += xs[3][e] * w;
    }
    const float bb = fb1[f];
    hs[0][f] = fmaxf(a0 + bb, 0.f);
    hs[1][f] = fmaxf(a1 + bb, 0.f);
    hs[2][f] = fmaxf(a2 + bb, 0.f);
    hs[3][f] = fmaxf(a3 + bb, 0.f);
  }
  __syncthreads();

  float a0 = 0, a1 = 0, a2 = 0, a3 = 0;
  for (int f = 0; f < F; ++f) {
    const float w = W2[f * D + t];
    a0 += hs[0][f] * w; a1 += hs[1][f] * w; a2 += hs[2][f] * w; a3 += hs[3][f] * w;
  }
  const float bb = fb2[t], g = g2[t], be = b2v[t];
  float accs[4] = {a0, a1, a2, a3};
  #pragma unroll
  for (int r = 0; r < 4; ++r) {
    const float tv = accs[r] + bb + xs[r][t];
    float s = tv, sq = tv * tv;
    #pragma unroll
    for (int o = 32; o > 0; o >>= 1) { s += __shfl_down(s, o, 64); sq += __shfl_down(sq, o, 64); }
    if ((t & 63) == 0) { red[(t >> 6) * 2] = s; red[(t >> 6) * 2 + 1] = sq; }
    __syncthreads();
    const float mean = (red[0] + red[2]) * (1.f / 128.f);
    const float var  = (red[1] + red[3]) * (1.f / 128.f) - mean * mean;
    __syncthreads();
    const float xn = (tv - mean) * __frsqrt_rn(var + EPS) * g + be;
    xbuf[(size_t)(row0 + r) * D + t] = xn;
    if (outp) outp[(size_t)(row0 + r) * D + t] = xn;   // fp32 output
  }
}

// ---------------------------------------------------------------------------
extern "C" void kernel_launch(void* const* d_in, const int* in_sizes, int n_in,
                              void* d_out, int out_size, void* d_ws, size_t ws_size,
                              hipStream_t stream) {
  // ws layout (4-byte units)
  int*   flags = (int*)d_ws;                 // [0]=isbf16 [1]=mask bytes/elem
  int*   mbuf  = flags + 16;                 // 1024 ints
  float* xbuf  = (float*)d_ws + 1040;        // 1024*128
  float* qb    = xbuf + NROW * D;
  float* kb    = qb + NROW * D;
  float* vb    = kb + NROW * D;
  float* W     = vb + NROW * D;              // W_TOTAL floats

  NormArgs na;
  {
    int off = 0;
    for (int i = 0; i < NT; ++i) {
      na.s[i] = d_in[i + 1];
      na.d[i] = W + off;
      na.c[i] = CNT[i];
      off += CNT[i];
    }
  }
  const int* agent_id = (const int*)d_in[30];

  k_detect<<<1, 256, 0, stream>>>(d_in[9] /*bn_v*/, d_in[29] /*mask*/, flags, mbuf);
  k_norm<<<dim3(192, NT), 256, 0, stream>>>(na, flags);
  k_relchain<<<NROW, 128, 0, stream>>>(d_in[0], W, flags, mbuf, agent_id, xbuf);

  for (int l = 0; l < 3; ++l) {
    k_qkv<<<NROW / 4, 128, 0, stream>>>(xbuf,
        W + OFF_WQ + l * D * D, W + OFF_BQ + l * D,
        W + OFF_WK + l * D * D, W + OFF_BK + l * D,
        W + OFF_WV + l * D * D, W + OFF_BV + l * D,
        qb, kb, vb);
    k_attn<<<NROW / 4, 128, 0, stream>>>(qb, kb, vb,
        W + OFF_WO + l * D * D, W + OFF_BO + l * D,
        W + OFF_LN1G + l * D, W + OFF_LN1B + l * D, mbuf, xbuf);
    k_ffn<<<NROW / 4, 128, 0, stream>>>(
        W + OFF_FW1 + l * D * F, W + OFF_FB1 + l * F,
        W + OFF_FW2 + l * F * D, W + OFF_FB2 + l * D,
        W + OFF_LN2G + l * D, W + OFF_LN2B + l * D,
        xbuf, (l == 2) ? (float*)d_out : (float*)nullptr);
  }
}

// Round 4
// 202.193 us; speedup vs baseline: 1.6692x; 1.6692x over previous
//
#include <hip/hip_runtime.h>
#include <hip/hip_bf16.h>

typedef unsigned short u16;
typedef unsigned int u32;
typedef unsigned char u8;

#define DEV __device__ __forceinline__

DEV float bf2f(u16 u) {
  union { u32 i; float f; } c; c.i = ((u32)u) << 16; return c.f;
}

static constexpr int B = 2, N = 512, D = 128, F = 512;
static constexpr int NROW = B * N;  // 1024
static constexpr float EPS = 1e-5f;
static constexpr float NEG = -1e9f;
static constexpr float SCALE = 0.08838834764831845f;  // 1/sqrt(128)

// ---- normalized-weight region: element offsets (order = d_in[1..28]) ------
static constexpr int NT = 28;
static constexpr int CNT[NT] = {
  256, 128, 32768, 128, 16384, 128, 128, 128, 128, 16384, 128, 16384,
  49152, 384, 49152, 384, 49152, 384, 49152, 384, 384, 384, 384, 384,
  196608, 1536, 196608, 384};
#define OFF_PRE_W   0
#define OFF_PRE_B   256
#define OFF_PROJ_W  384
#define OFF_PROJ_B  33152
#define OFF_OUT_W1  33280
#define OFF_BN_G    49664
#define OFF_BN_B    49792
#define OFF_BN_M    49920
#define OFF_BN_V    50048
#define OFF_OUT_W2  50176
#define OFF_OUT_B2  66560
#define OFF_PE      66688
#define OFF_WQ      83072
#define OFF_BQ      132224
#define OFF_WK      132608
#define OFF_BK      181760
#define OFF_WV      182144
#define OFF_BV      231296
#define OFF_WO      231680
#define OFF_BO      280832
#define OFF_LN1G    281216
#define OFF_LN1B    281600
#define OFF_LN2G    281984
#define OFF_LN2B    282368
#define OFF_FW1     282752
#define OFF_FB1     479360
#define OFF_FW2     480896
#define OFF_FB2     677504
#define W_TOTAL     677888

struct NormArgs { const void* s[NT]; float* d[NT]; int c[NT]; };

// ---------------------------------------------------------------------------
// k_detect: classify input encodings + normalize mask to int 0/1.
// ---------------------------------------------------------------------------
__global__ __launch_bounds__(256) void k_detect(
    const void* __restrict__ bnv, const void* __restrict__ maskp,
    int* __restrict__ flags, int* __restrict__ mbuf)
{
  const int t = threadIdx.x;
  __shared__ int s_nf, s_m4, s_m2;
  if (t == 0) { s_nf = 0; s_m4 = 0; s_m2 = 0; }
  __syncthreads();
  if (t < 64) {
    const u32 w = ((const u32*)bnv)[t];
    if (((w >> 8) & 0xFFu) != 0x3Fu || ((w >> 24) & 0xFFu) != 0x3Fu)
      atomicOr(&s_nf, 1);
  }
  {
    const u32 w = ((const u32*)maskp)[t];
    if (!(w == 0u || w == 1u || w == 0x3F800000u)) atomicOr(&s_m4, 1);
    if (!(w == 0u || w == 1u || w == 0x10000u || w == 0x10001u ||
          w == 0x3F80u || w == 0x3F800000u || w == 0x3F803F80u)) atomicOr(&s_m2, 1);
  }
  __syncthreads();
  const int isb  = s_nf ? 0 : 1;
  const int mode = (!s_m4) ? 4 : ((!s_m2) ? 2 : 1);  // bytes per mask element
  if (t == 0) { flags[0] = isb; flags[1] = mode; }
  #pragma unroll
  for (int k = 0; k < 4; ++k) {
    const int e = k * 256 + t;
    int v;
    if (mode == 4)      v = (((const u32*)maskp)[e] != 0u);
    else if (mode == 2) v = (((const u16*)maskp)[e] != 0);
    else                v = (((const u8*)maskp)[e]  != 0);
    mbuf[e] = v;
  }
}

// ---------------------------------------------------------------------------
// k_norm: convert all float tensors (fp32 or bf16 source) to fp32 in ws.
// ---------------------------------------------------------------------------
__global__ __launch_bounds__(256) void k_norm(NormArgs a, const int* __restrict__ flags) {
  const int ten = blockIdx.y;
  const int n = a.c[ten];
  const int base = blockIdx.x * 1024 + threadIdx.x;
  const int isb = flags[0];
  const float* __restrict__ sf = (const float*)a.s[ten];
  const u16*   __restrict__ sh = (const u16*)a.s[ten];
  float* __restrict__ d = a.d[ten];
  #pragma unroll
  for (int k = 0; k < 4; ++k) {
    const int e = base + k * 256;
    if (e < n) d[e] = isb ? bf2f(sh[e]) : sf[e];
  }
}

// ---------------------------------------------------------------------------
// k_relchain: collapsed pairwise-relation chain + out-MLP + pos embedding.
// ---------------------------------------------------------------------------
__global__ __launch_bounds__(128) void k_relchain(
    const void* __restrict__ relv, const float* __restrict__ W,
    const int* __restrict__ flags, const int* __restrict__ mbuf,
    const int* __restrict__ agent_id, float* __restrict__ xbuf)
{
  const int bi = blockIdx.x;      // b*N + i
  const int b  = bi >> 9;
  const int t  = threadIdx.x;     // 0..127

  __shared__ float red[6];
  __shared__ float pl[D], zl[D], rl[D];

  float s0 = 0.f, s1 = 0.f, cnt = 0.f;
  if (flags[0]) {
    const u32* rel2 = (const u32*)relv;  // packed bf16 pair per (b,i,j)
    #pragma unroll
    for (int jj = 0; jj < 4; ++jj) {
      const int j = jj * 128 + t;
      const float m = (float)mbuf[b * N + j];
      const u32 u = rel2[(size_t)bi * N + j];
      s0 += m * bf2f((u16)(u & 0xFFFFu));
      s1 += m * bf2f((u16)(u >> 16));
      cnt += m;
    }
  } else {
    const float2* relf = (const float2*)relv;
    #pragma unroll
    for (int jj = 0; jj < 4; ++jj) {
      const int j = jj * 128 + t;
      const float m = (float)mbuf[b * N + j];
      const float2 u = relf[(size_t)bi * N + j];
      s0 += m * u.x; s1 += m * u.y; cnt += m;
    }
  }
  #pragma unroll
  for (int o = 32; o > 0; o >>= 1) {
    s0 += __shfl_down(s0, o, 64);
    s1 += __shfl_down(s1, o, 64);
    cnt += __shfl_down(cnt, o, 64);
  }
  if ((t & 63) == 0) {
    const int w = t >> 6;
    red[w * 3 + 0] = s0; red[w * 3 + 1] = s1; red[w * 3 + 2] = cnt;
  }
  __syncthreads();
  const float T0 = red[0] + red[3], T1 = red[1] + red[4], Mtot = red[2] + red[5];
  const int maski = mbuf[bi];

  float pooled = 0.f;
  if (maski)  // maski==1 implies Mtot>=1 (the j==i term)
    pooled = (T0 * W[OFF_PRE_W + t] + T1 * W[OFF_PRE_W + D + t]) / Mtot + W[OFF_PRE_B + t];
  pl[t] = pooled;
  __syncthreads();

  float z = 0.f;
  if (maski) {
    float acc = 0.f;
    for (int e = 0; e < D; ++e)
      acc += pl[e] * (W[OFF_PROJ_W + e * D + t] + W[OFF_PROJ_W + (e + D) * D + t]);
    z = acc + W[OFF_PROJ_B + t];
  }
  zl[t] = z;
  __syncthreads();

  float h = 0.f;
  for (int e = 0; e < D; ++e) h += zl[e] * W[OFF_OUT_W1 + e * D + t];
  const float hb = (h - W[OFF_BN_M + t]) * __frsqrt_rn(W[OFF_BN_V + t] + EPS)
                   * W[OFF_BN_G + t] + W[OFF_BN_B + t];
  rl[t] = fmaxf(hb, 0.f);
  __syncthreads();

  float o2 = 0.f;
  for (int e = 0; e < D; ++e) o2 += rl[e] * W[OFF_OUT_W2 + e * D + t];
  const int aid = agent_id[bi];
  xbuf[(size_t)bi * D + t] = o2 + W[OFF_OUT_B2 + t] + W[OFF_PE + aid * D + t];
}

// ---------------------------------------------------------------------------
// k_qkv v2: grid (NROW, 3); y=0: Q -> qb[row][d], y=1: K -> kbT[b][d][i]
// (transposed for coalesced score pass), y=2: V -> vb[row][d].
// ---------------------------------------------------------------------------
__global__ __launch_bounds__(128) void k_qkv(
    const float* __restrict__ xbuf,
    const float* __restrict__ WQ, const float* __restrict__ bq,
    const float* __restrict__ WK, const float* __restrict__ bk,
    const float* __restrict__ WV, const float* __restrict__ bv,
    float* __restrict__ qb, float* __restrict__ kbT, float* __restrict__ vb)
{
  const int t = threadIdx.x;
  const int row = blockIdx.x;
  const int y = blockIdx.y;
  const int b = row >> 9, i = row & 511;
  __shared__ float xs[D];
  xs[t] = xbuf[(size_t)row * D + t];
  __syncthreads();

  const float* Wm = (y == 0) ? WQ : (y == 1) ? WK : WV;
  const float* bm = (y == 0) ? bq : (y == 1) ? bk : bv;
  float acc = 0.f;
  #pragma unroll 8
  for (int e = 0; e < D; ++e) acc += xs[e] * Wm[e * D + t];
  acc += bm[t];
  if (y == 0)      qb[(size_t)row * D + t] = acc;
  else if (y == 1) kbT[(size_t)b * D * N + (size_t)t * N + i] = acc;
  else             vb[(size_t)row * D + t] = acc;
}

// ---------------------------------------------------------------------------
// k_attn v2: 1 row/block, 512 threads (8 waves).
// scores (coalesced via kbT) -> softmax -> AV (split-K) -> WO (split-K)
// -> residual + LN1. In-place xbuf update (block-private row).
// ---------------------------------------------------------------------------
__global__ __launch_bounds__(512) void k_attn(
    const float* __restrict__ qb, const float* __restrict__ kbT, const float* __restrict__ vb,
    const float* __restrict__ WO, const float* __restrict__ bo,
    const float* __restrict__ g1, const float* __restrict__ b1,
    const int* __restrict__ mbuf, float* __restrict__ xbuf)
{
  const int t = threadIdx.x;           // 0..511
  const int row = blockIdx.x;
  const int b = row >> 9;
  const int wid = t >> 6;              // wave id 0..7

  __shared__ float qs[D];
  __shared__ float p[N];
  __shared__ float part[4][D];
  __shared__ float os[D];
  __shared__ float red[8];
  __shared__ float redS[2], redQ[2];

  if (t < D) qs[t] = qb[(size_t)row * D + t];
  __syncthreads();

  // scores: thread t owns key j = t
  float acc = 0.f;
  {
    const float* kcol = kbT + (size_t)b * D * N + t;
    #pragma unroll 8
    for (int e = 0; e < D; ++e) acc += qs[e] * kcol[(size_t)e * N];
  }
  const float pv = acc * SCALE + (mbuf[b * N + t] ? 0.f : NEG);

  // softmax over 512 (8 waves)
  float lm = pv;
  #pragma unroll
  for (int o = 32; o > 0; o >>= 1) lm = fmaxf(lm, __shfl_xor(lm, o, 64));
  if ((t & 63) == 0) red[wid] = lm;
  __syncthreads();
  float mx = red[0];
  #pragma unroll
  for (int w = 1; w < 8; ++w) mx = fmaxf(mx, red[w]);
  const float ev = __expf(pv - mx);
  p[t] = ev;
  float ls = ev;
  #pragma unroll
  for (int o = 32; o > 0; o >>= 1) ls += __shfl_xor(ls, o, 64);
  __syncthreads();               // protect red reuse
  if ((t & 63) == 0) red[wid] = ls;
  __syncthreads();
  float den = red[0];
  #pragma unroll
  for (int w = 1; w < 8; ++w) den += red[w];

  // AV: d = t&127, j-quarter = t>>7
  {
    const int d = t & 127, fq = t >> 7;
    const float* vp = vb + ((size_t)b * N + fq * 128) * D + d;
    float a = 0.f;
    #pragma unroll 8
    for (int jj = 0; jj < 128; ++jj) a += p[fq * 128 + jj] * vp[(size_t)jj * D];
    part[fq][d] = a;
  }
  __syncthreads();
  if (t < D) os[t] = (part[0][t] + part[1][t] + part[2][t] + part[3][t]) / den;
  __syncthreads();

  // WO: d = t&127, e-quarter = t>>7 (32 e's each)
  {
    const int d = t & 127, eq = t >> 7;
    float a = 0.f;
    #pragma unroll 8
    for (int ee = 0; ee < 32; ++ee) {
      const int e = eq * 32 + ee;
      a += os[e] * WO[e * D + d];
    }
    part[eq][d] = a;
  }
  __syncthreads();

  // residual + LN1 on threads 0..127 (waves 0,1)
  float tv = 0.f;
  if (t < D)
    tv = part[0][t] + part[1][t] + part[2][t] + part[3][t] + bo[t]
       + xbuf[(size_t)row * D + t];
  float s = tv, sq = tv * tv;
  #pragma unroll
  for (int o = 32; o > 0; o >>= 1) { s += __shfl_xor(s, o, 64); sq += __shfl_xor(sq, o, 64); }
  if (t < D && (t & 63) == 0) { redS[t >> 6] = s; redQ[t >> 6] = sq; }
  __syncthreads();
  if (t < D) {
    const float mean = (redS[0] + redS[1]) * (1.f / 128.f);
    const float var  = (redQ[0] + redQ[1]) * (1.f / 128.f) - mean * mean;
    xbuf[(size_t)row * D + t] = (tv - mean) * __frsqrt_rn(var + EPS) * g1[t] + b1[t];
  }
}

// ---------------------------------------------------------------------------
// k_ffn v2: 1 row/block, 512 threads. h[f=t] -> split-K second GEMM ->
// residual + LN2; last layer writes fp32 d_out.
// ---------------------------------------------------------------------------
__global__ __launch_bounds__(512) void k_ffn(
    const float* __restrict__ W1, const float* __restrict__ fb1,
    const float* __restrict__ W2, const float* __restrict__ fb2,
    const float* __restrict__ g2, const float* __restrict__ b2v,
    float* __restrict__ xbuf, float* __restrict__ outp)
{
  const int t = threadIdx.x;           // 0..511
  const int row = blockIdx.x;

  __shared__ float xs[D];
  __shared__ float hs[F];
  __shared__ float part[4][D];
  __shared__ float redS[2], redQ[2];

  if (t < D) xs[t] = xbuf[(size_t)row * D + t];
  __syncthreads();

  // phase 1: h[f = t]
  {
    float a = 0.f;
    #pragma unroll 8
    for (int e = 0; e < D; ++e) a += xs[e] * W1[(size_t)e * F + t];
    hs[t] = fmaxf(a + fb1[t], 0.f);
  }
  __syncthreads();

  // phase 2: d = t&127, f-quarter = t>>7
  {
    const int d = t & 127, fq = t >> 7;
    float a = 0.f;
    #pragma unroll 8
    for (int jj = 0; jj < 128; ++jj) {
      const int f = fq * 128 + jj;
      a += hs[f] * W2[(size_t)f * D + d];
    }
    part[fq][d] = a;
  }
  __syncthreads();

  float tv = 0.f;
  if (t < D)
    tv = part[0][t] + part[1][t] + part[2][t] + part[3][t] + fb2[t] + xs[t];
  float s = tv, sq = tv * tv;
  #pragma unroll
  for (int o = 32; o > 0; o >>= 1) { s += __shfl_xor(s, o, 64); sq += __shfl_xor(sq, o, 64); }
  if (t < D && (t & 63) == 0) { redS[t >> 6] = s; redQ[t >> 6] = sq; }
  __syncthreads();
  if (t < D) {
    const float mean = (redS[0] + redS[1]) * (1.f / 128.f);
    const float var  = (redQ[0] + redQ[1]) * (1.f / 128.f) - mean * mean;
    const float xn = (tv - mean) * __frsqrt_rn(var + EPS) * g2[t] + b2v[t];
    xbuf[(size_t)row * D + t] = xn;
    if (outp) outp[(size_t)row * D + t] = xn;   // fp32 output
  }
}

// ---------------------------------------------------------------------------
extern "C" void kernel_launch(void* const* d_in, const int* in_sizes, int n_in,
                              void* d_out, int out_size, void* d_ws, size_t ws_size,
                              hipStream_t stream) {
  // ws layout (4-byte units)
  int*   flags = (int*)d_ws;                 // [0]=isbf16 [1]=mask bytes/elem
  int*   mbuf  = flags + 16;                 // 1024 ints
  float* xbuf  = (float*)d_ws + 1040;        // 1024*128
  float* qb    = xbuf + NROW * D;
  float* kbT   = qb + NROW * D;              // [B][D][N] transposed K
  float* vb    = kbT + NROW * D;
  float* W     = vb + NROW * D;              // W_TOTAL floats

  NormArgs na;
  {
    int off = 0;
    for (int i = 0; i < NT; ++i) {
      na.s[i] = d_in[i + 1];
      na.d[i] = W + off;
      na.c[i] = CNT[i];
      off += CNT[i];
    }
  }
  const int* agent_id = (const int*)d_in[30];

  k_detect<<<1, 256, 0, stream>>>(d_in[9] /*bn_v*/, d_in[29] /*mask*/, flags, mbuf);
  k_norm<<<dim3(192, NT), 256, 0, stream>>>(na, flags);
  k_relchain<<<NROW, 128, 0, stream>>>(d_in[0], W, flags, mbuf, agent_id, xbuf);

  for (int l = 0; l < 3; ++l) {
    k_qkv<<<dim3(NROW, 3), 128, 0, stream>>>(xbuf,
        W + OFF_WQ + l * D * D, W + OFF_BQ + l * D,
        W + OFF_WK + l * D * D, W + OFF_BK + l * D,
        W + OFF_WV + l * D * D, W + OFF_BV + l * D,
        qb, kbT, vb);
    k_attn<<<NROW, 512, 0, stream>>>(qb, kbT, vb,
        W + OFF_WO + l * D * D, W + OFF_BO + l * D,
        W + OFF_LN1G + l * D, W + OFF_LN1B + l * D, mbuf, xbuf);
    k_ffn<<<NROW, 512, 0, stream>>>(
        W + OFF_FW1 + l * D * F, W + OFF_FB1 + l * F,
        W + OFF_FW2 + l * F * D, W + OFF_FB2 + l * D,
        W + OFF_LN2G + l * D, W + OFF_LN2B + l * D,
        xbuf, (l == 2) ? (float*)d_out : (float*)nullptr);
  }
}

// Round 5
// 132.269 us; speedup vs baseline: 2.5517x; 1.5287x over previous
//
#include <hip/hip_runtime.h>
#include <hip/hip_bf16.h>

typedef unsigned short u16;
typedef unsigned int u32;
typedef unsigned char u8;

#define DEV __device__ __forceinline__

DEV float bf2f(u16 u) {
  union { u32 i; float f; } c; c.i = ((u32)u) << 16; return c.f;
}

static constexpr int B = 2, N = 512, D = 128, F = 512;
static constexpr int NROW = B * N;  // 1024
static constexpr float EPS = 1e-5f;
static constexpr float NEG = -1e9f;
static constexpr float SCALE = 0.08838834764831845f;  // 1/sqrt(128)

// ---- normalized-weight region: element offsets (order = d_in[1..28]) ------
static constexpr int NT = 28;
static constexpr int CNT[NT] = {
  256, 128, 32768, 128, 16384, 128, 128, 128, 128, 16384, 128, 16384,
  49152, 384, 49152, 384, 49152, 384, 49152, 384, 384, 384, 384, 384,
  196608, 1536, 196608, 384};
#define OFF_PRE_W   0
#define OFF_PRE_B   256
#define OFF_PROJ_W  384
#define OFF_PROJ_B  33152
#define OFF_OUT_W1  33280
#define OFF_BN_G    49664
#define OFF_BN_B    49792
#define OFF_BN_M    49920
#define OFF_BN_V    50048
#define OFF_OUT_W2  50176
#define OFF_OUT_B2  66560
#define OFF_PE      66688
#define OFF_WQ      83072
#define OFF_BQ      132224
#define OFF_WK      132608
#define OFF_BK      181760
#define OFF_WV      182144
#define OFF_BV      231296
#define OFF_WO      231680
#define OFF_BO      280832
#define OFF_LN1G    281216
#define OFF_LN1B    281600
#define OFF_LN2G    281984
#define OFF_LN2B    282368
#define OFF_FW1     282752
#define OFF_FB1     479360
#define OFF_FW2     480896
#define OFF_FB2     677504
#define W_TOTAL     677888

struct NormArgs { const void* s[NT]; float* d[NT]; int c[NT]; };

// ---------------------------------------------------------------------------
// k_detect: classify input encodings + normalize mask to int 0/1.
// ---------------------------------------------------------------------------
__global__ __launch_bounds__(256) void k_detect(
    const void* __restrict__ bnv, const void* __restrict__ maskp,
    int* __restrict__ flags, int* __restrict__ mbuf)
{
  const int t = threadIdx.x;
  __shared__ int s_nf, s_m4, s_m2;
  if (t == 0) { s_nf = 0; s_m4 = 0; s_m2 = 0; }
  __syncthreads();
  if (t < 64) {
    const u32 w = ((const u32*)bnv)[t];
    if (((w >> 8) & 0xFFu) != 0x3Fu || ((w >> 24) & 0xFFu) != 0x3Fu)
      atomicOr(&s_nf, 1);
  }
  {
    const u32 w = ((const u32*)maskp)[t];
    if (!(w == 0u || w == 1u || w == 0x3F800000u)) atomicOr(&s_m4, 1);
    if (!(w == 0u || w == 1u || w == 0x10000u || w == 0x10001u ||
          w == 0x3F80u || w == 0x3F800000u || w == 0x3F803F80u)) atomicOr(&s_m2, 1);
  }
  __syncthreads();
  const int isb  = s_nf ? 0 : 1;
  const int mode = (!s_m4) ? 4 : ((!s_m2) ? 2 : 1);  // bytes per mask element
  if (t == 0) { flags[0] = isb; flags[1] = mode; }
  #pragma unroll
  for (int k = 0; k < 4; ++k) {
    const int e = k * 256 + t;
    int v;
    if (mode == 4)      v = (((const u32*)maskp)[e] != 0u);
    else if (mode == 2) v = (((const u16*)maskp)[e] != 0);
    else                v = (((const u8*)maskp)[e]  != 0);
    mbuf[e] = v;
  }
}

// ---------------------------------------------------------------------------
// k_norm: convert all float tensors (fp32 or bf16 source) to fp32 in ws.
// grid (64, NT), grid-stride over each tensor.
// ---------------------------------------------------------------------------
__global__ __launch_bounds__(256) void k_norm(NormArgs a, const int* __restrict__ flags) {
  const int ten = blockIdx.y;
  const int n = a.c[ten];
  const int isb = flags[0];
  const float* __restrict__ sf = (const float*)a.s[ten];
  const u16*   __restrict__ sh = (const u16*)a.s[ten];
  float* __restrict__ d = a.d[ten];
  for (int e = blockIdx.x * 256 + threadIdx.x; e < n; e += 64 * 256)
    d[e] = isb ? bf2f(sh[e]) : sf[e];
}

// ---------------------------------------------------------------------------
// k_relq: collapsed pairwise-relation chain + out-MLP + PE + QKV(layer 0).
// 4 rows/block, 256 blocks, 512 threads.
// ---------------------------------------------------------------------------
__global__ __launch_bounds__(512) void k_relq(
    const void* __restrict__ relv, const float* __restrict__ W,
    const int* __restrict__ flags, const int* __restrict__ mbuf,
    const int* __restrict__ agent_id, float* __restrict__ xbuf,
    float* __restrict__ qb, float* __restrict__ kbT, float* __restrict__ vb)
{
  const int t = threadIdx.x;            // 0..511
  const int row0 = blockIdx.x * 4;
  const int b = row0 >> 9;
  const int wid = t >> 6;

  __shared__ float pl[4][D], zl[4][D], rl[4][D], os[4][D];
  __shared__ float part[4][4][D];
  __shared__ float wred[8][9];
  __shared__ float sT0[4], sT1[4], sMt;

  // --- P1: masked sums over j of rel channels; Mtot ---
  float s0[4] = {0, 0, 0, 0}, s1[4] = {0, 0, 0, 0}, cnt;
  {
    const int j = t;
    const float m = (float)mbuf[b * N + j];
    cnt = m;
    if (flags[0]) {
      const u32* rel2 = (const u32*)relv;
      #pragma unroll
      for (int r = 0; r < 4; ++r) {
        const u32 u = rel2[(size_t)(row0 + r) * N + j];
        s0[r] += m * bf2f((u16)(u & 0xFFFFu));
        s1[r] += m * bf2f((u16)(u >> 16));
      }
    } else {
      const float2* relf = (const float2*)relv;
      #pragma unroll
      for (int r = 0; r < 4; ++r) {
        const float2 u = relf[(size_t)(row0 + r) * N + j];
        s0[r] += m * u.x; s1[r] += m * u.y;
      }
    }
  }
  #pragma unroll
  for (int o = 32; o > 0; o >>= 1) {
    #pragma unroll
    for (int r = 0; r < 4; ++r) {
      s0[r] += __shfl_xor(s0[r], o, 64);
      s1[r] += __shfl_xor(s1[r], o, 64);
    }
    cnt += __shfl_xor(cnt, o, 64);
  }
  if ((t & 63) == 0) {
    #pragma unroll
    for (int r = 0; r < 4; ++r) { wred[wid][r] = s0[r]; wred[wid][4 + r] = s1[r]; }
    wred[wid][8] = cnt;
  }
  __syncthreads();
  if (t < 4) {
    float a0 = 0, a1 = 0;
    #pragma unroll
    for (int w = 0; w < 8; ++w) { a0 += wred[w][t]; a1 += wred[w][4 + t]; }
    sT0[t] = a0; sT1[t] = a1;
  }
  if (t == 8) {
    float c = 0;
    #pragma unroll
    for (int w = 0; w < 8; ++w) c += wred[w][8];
    sMt = c;
  }
  __syncthreads();

  // --- P2: pooled ---
  {
    const int r = t >> 7, c = t & 127;
    const int mi = mbuf[row0 + r];
    pl[r][c] = mi ? (sT0[r] * W[OFF_PRE_W + c] + sT1[r] * W[OFF_PRE_W + D + c]) / sMt
                    + W[OFF_PRE_B + c]
                  : 0.f;
  }
  __syncthreads();

  // --- P3: z = pooled @ (P1+P2) + proj_b (masked) ---
  {
    const int d = t & 127, eq = t >> 7;
    float a[4] = {0, 0, 0, 0};
    #pragma unroll 8
    for (int ee = 0; ee < 32; ++ee) {
      const int e = eq * 32 + ee;
      const float w = W[OFF_PROJ_W + e * D + d] + W[OFF_PROJ_W + (e + D) * D + d];
      #pragma unroll
      for (int r = 0; r < 4; ++r) a[r] += pl[r][e] * w;
    }
    #pragma unroll
    for (int r = 0; r < 4; ++r) part[eq][r][d] = a[r];
  }
  __syncthreads();
  {
    const int r = t >> 7, d = t & 127;
    zl[r][d] = mbuf[row0 + r]
             ? part[0][r][d] + part[1][r][d] + part[2][r][d] + part[3][r][d]
               + W[OFF_PROJ_B + d]
             : 0.f;
  }
  __syncthreads();

  // --- P4: h = z @ out_w1; bn; relu ---
  {
    const int d = t & 127, eq = t >> 7;
    float a[4] = {0, 0, 0, 0};
    #pragma unroll 8
    for (int ee = 0; ee < 32; ++ee) {
      const int e = eq * 32 + ee;
      const float w = W[OFF_OUT_W1 + e * D + d];
      #pragma unroll
      for (int r = 0; r < 4; ++r) a[r] += zl[r][e] * w;
    }
    #pragma unroll
    for (int r = 0; r < 4; ++r) part[eq][r][d] = a[r];
  }
  __syncthreads();
  {
    const int r = t >> 7, d = t & 127;
    const float h = part[0][r][d] + part[1][r][d] + part[2][r][d] + part[3][r][d];
    const float hb = (h - W[OFF_BN_M + d]) * __frsqrt_rn(W[OFF_BN_V + d] + EPS)
                     * W[OFF_BN_G + d] + W[OFF_BN_B + d];
    rl[r][d] = fmaxf(hb, 0.f);
  }
  __syncthreads();

  // --- P5: x0 = relu_h @ out_w2 + out_b2 + pe[agent_id] ---
  {
    const int d = t & 127, eq = t >> 7;
    float a[4] = {0, 0, 0, 0};
    #pragma unroll 8
    for (int ee = 0; ee < 32; ++ee) {
      const int e = eq * 32 + ee;
      const float w = W[OFF_OUT_W2 + e * D + d];
      #pragma unroll
      for (int r = 0; r < 4; ++r) a[r] += rl[r][e] * w;
    }
    #pragma unroll
    for (int r = 0; r < 4; ++r) part[eq][r][d] = a[r];
  }
  __syncthreads();
  {
    const int r = t >> 7, d = t & 127;
    const int aid = agent_id[row0 + r];
    const float x0 = part[0][r][d] + part[1][r][d] + part[2][r][d] + part[3][r][d]
                   + W[OFF_OUT_B2 + d] + W[OFF_PE + aid * D + d];
    os[r][d] = x0;
    xbuf[(size_t)(row0 + r) * D + d] = x0;
  }
  __syncthreads();

  // --- P6: QKV layer 0 ---
  {
    const int c = t & 127, m = t >> 7;
    if (m < 3) {
      const float* Wm = W + ((m == 0) ? OFF_WQ : (m == 1) ? OFF_WK : OFF_WV);
      const float* bm = W + ((m == 0) ? OFF_BQ : (m == 1) ? OFF_BK : OFF_BV);
      float a[4] = {0, 0, 0, 0};
      #pragma unroll 8
      for (int e = 0; e < D; ++e) {
        const float w = Wm[e * D + c];
        #pragma unroll
        for (int r = 0; r < 4; ++r) a[r] += os[r][e] * w;
      }
      const float bv_ = bm[c];
      const int i0 = row0 & 511;
      #pragma unroll
      for (int r = 0; r < 4; ++r) {
        const float v = a[r] + bv_;
        if (m == 0)      qb[(size_t)(row0 + r) * D + c] = v;
        else if (m == 1) kbT[(size_t)b * D * N + (size_t)c * N + i0 + r] = v;
        else             vb[(size_t)(row0 + r) * D + c] = v;
      }
    }
  }
}

// ---------------------------------------------------------------------------
// k_layer: fused attn + LN1 + FFN + LN2 [+ QKV(l+1)] for 4 rows/block.
// 256 blocks, 512 threads. Q/K/V ping-pong between buffer sets.
// ---------------------------------------------------------------------------
__global__ __launch_bounds__(512) void k_layer(
    const float* __restrict__ qin, const float* __restrict__ kinT, const float* __restrict__ vin,
    const float* __restrict__ WO, const float* __restrict__ bo,
    const float* __restrict__ g1, const float* __restrict__ b1,
    const float* __restrict__ W1, const float* __restrict__ fb1,
    const float* __restrict__ W2, const float* __restrict__ fb2,
    const float* __restrict__ g2, const float* __restrict__ b2v,
    const float* __restrict__ WQn, const float* __restrict__ bqn,
    const float* __restrict__ WKn, const float* __restrict__ bkn,
    const float* __restrict__ WVn, const float* __restrict__ bvn,
    float* __restrict__ qout, float* __restrict__ koutT, float* __restrict__ vout,
    const int* __restrict__ mbuf, float* __restrict__ xbuf, float* __restrict__ outp)
{
  const int t = threadIdx.x;            // 0..511
  const int row0 = blockIdx.x * 4;
  const int b = row0 >> 9;
  const int wid = t >> 6;

  __shared__ float qs[4][D];
  __shared__ float p[4][N];
  __shared__ float part[4][4][D];
  __shared__ float os[4][D];
  __shared__ float xs[4][D];
  __shared__ float hs[4][F];
  __shared__ float den[4];

  // A: load Q rows
  {
    const int r = t >> 7, d = t & 127;
    qs[r][d] = qin[(size_t)(row0 + r) * D + d];
  }
  __syncthreads();

  // B: scores — thread t owns key j=t
  {
    const float* kcol = kinT + (size_t)b * D * N + t;
    float a[4] = {0, 0, 0, 0};
    #pragma unroll 8
    for (int e = 0; e < D; ++e) {
      const float kv = kcol[(size_t)e * N];
      #pragma unroll
      for (int r = 0; r < 4; ++r) a[r] += qs[r][e] * kv;
    }
    const float bias = mbuf[b * N + t] ? 0.f : NEG;
    #pragma unroll
    for (int r = 0; r < 4; ++r) p[r][t] = a[r] * SCALE + bias;
  }
  __syncthreads();

  // C: softmax — wave w handles row w (waves 4..7 idle)
  if (wid < 4) {
    const int r = wid, lane = t & 63;
    float pv[8];
    float mx = -1e30f;
    #pragma unroll
    for (int k = 0; k < 8; ++k) { pv[k] = p[r][lane + 64 * k]; mx = fmaxf(mx, pv[k]); }
    #pragma unroll
    for (int o = 32; o > 0; o >>= 1) mx = fmaxf(mx, __shfl_xor(mx, o, 64));
    float sum = 0.f;
    #pragma unroll
    for (int k = 0; k < 8; ++k) { pv[k] = __expf(pv[k] - mx); sum += pv[k]; }
    #pragma unroll
    for (int o = 32; o > 0; o >>= 1) sum += __shfl_xor(sum, o, 64);
    #pragma unroll
    for (int k = 0; k < 8; ++k) p[r][lane + 64 * k] = pv[k];
    if (lane == 0) den[r] = sum;
  }
  __syncthreads();

  // D: AV — d = t&127, j-quarter = t>>7
  {
    const int d = t & 127, q4 = t >> 7;
    const float* vp = vin + ((size_t)b * N + q4 * 128) * D + d;
    float a[4] = {0, 0, 0, 0};
    #pragma unroll 8
    for (int jj = 0; jj < 128; ++jj) {
      const float vv = vp[(size_t)jj * D];
      #pragma unroll
      for (int r = 0; r < 4; ++r) a[r] += p[r][q4 * 128 + jj] * vv;
    }
    #pragma unroll
    for (int r = 0; r < 4; ++r) part[q4][r][d] = a[r];
  }
  __syncthreads();
  {
    const int r = t >> 7, d = t & 127;
    os[r][d] = (part[0][r][d] + part[1][r][d] + part[2][r][d] + part[3][r][d]) / den[r];
  }
  __syncthreads();

  // E: WO — d = t&127, e-quarter = t>>7
  {
    const int d = t & 127, eq = t >> 7;
    float a[4] = {0, 0, 0, 0};
    #pragma unroll 8
    for (int ee = 0; ee < 32; ++ee) {
      const int e = eq * 32 + ee;
      const float w = WO[e * D + d];
      #pragma unroll
      for (int r = 0; r < 4; ++r) a[r] += os[r][e] * w;
    }
    #pragma unroll
    for (int r = 0; r < 4; ++r) part[eq][r][d] = a[r];
  }
  __syncthreads();

  // F: residual + LN1 — wave w handles row w
  if (wid < 4) {
    const int r = wid, lane = t & 63;
    float tv[2];
    #pragma unroll
    for (int k = 0; k < 2; ++k) {
      const int d = lane + 64 * k;
      tv[k] = part[0][r][d] + part[1][r][d] + part[2][r][d] + part[3][r][d]
            + bo[d] + xbuf[(size_t)(row0 + r) * D + d];
    }
    float s = tv[0] + tv[1], sq = tv[0] * tv[0] + tv[1] * tv[1];
    #pragma unroll
    for (int o = 32; o > 0; o >>= 1) { s += __shfl_xor(s, o, 64); sq += __shfl_xor(sq, o, 64); }
    const float mean = s * (1.f / 128.f);
    const float var  = sq * (1.f / 128.f) - mean * mean;
    const float rstd = __frsqrt_rn(var + EPS);
    #pragma unroll
    for (int k = 0; k < 2; ++k) {
      const int d = lane + 64 * k;
      xs[r][d] = (tv[k] - mean) * rstd * g1[d] + b1[d];
    }
  }
  __syncthreads();

  // G: FFN1 — thread t owns f=t
  {
    float a[4] = {0, 0, 0, 0};
    #pragma unroll 8
    for (int e = 0; e < D; ++e) {
      const float w = W1[(size_t)e * F + t];
      #pragma unroll
      for (int r = 0; r < 4; ++r) a[r] += xs[r][e] * w;
    }
    const float bb = fb1[t];
    #pragma unroll
    for (int r = 0; r < 4; ++r) hs[r][t] = fmaxf(a[r] + bb, 0.f);
  }
  __syncthreads();

  // H: FFN2 — d = t&127, f-quarter = t>>7
  {
    const int d = t & 127, fq = t >> 7;
    float a[4] = {0, 0, 0, 0};
    #pragma unroll 8
    for (int jj = 0; jj < 128; ++jj) {
      const int f = fq * 128 + jj;
      const float w = W2[(size_t)f * D + d];
      #pragma unroll
      for (int r = 0; r < 4; ++r) a[r] += hs[r][f] * w;
    }
    #pragma unroll
    for (int r = 0; r < 4; ++r) part[fq][r][d] = a[r];
  }
  __syncthreads();

  // I: residual + LN2 — wave w handles row w; write x to os/xbuf (+outp)
  if (wid < 4) {
    const int r = wid, lane = t & 63;
    float tv[2];
    #pragma unroll
    for (int k = 0; k < 2; ++k) {
      const int d = lane + 64 * k;
      tv[k] = part[0][r][d] + part[1][r][d] + part[2][r][d] + part[3][r][d]
            + fb2[d] + xs[r][d];
    }
    float s = tv[0] + tv[1], sq = tv[0] * tv[0] + tv[1] * tv[1];
    #pragma unroll
    for (int o = 32; o > 0; o >>= 1) { s += __shfl_xor(s, o, 64); sq += __shfl_xor(sq, o, 64); }
    const float mean = s * (1.f / 128.f);
    const float var  = sq * (1.f / 128.f) - mean * mean;
    const float rstd = __frsqrt_rn(var + EPS);
    #pragma unroll
    for (int k = 0; k < 2; ++k) {
      const int d = lane + 64 * k;
      const float xn = (tv[k] - mean) * rstd * g2[d] + b2v[d];
      os[r][d] = xn;
      xbuf[(size_t)(row0 + r) * D + d] = xn;
      if (outp) outp[(size_t)(row0 + r) * D + d] = xn;
    }
  }
  __syncthreads();

  // J: QKV for next layer
  if (WQn) {
    const int c = t & 127, m = t >> 7;
    if (m < 3) {
      const float* Wm = (m == 0) ? WQn : (m == 1) ? WKn : WVn;
      const float* bm = (m == 0) ? bqn : (m == 1) ? bkn : bvn;
      float a[4] = {0, 0, 0, 0};
      #pragma unroll 8
      for (int e = 0; e < D; ++e) {
        const float w = Wm[e * D + c];
        #pragma unroll
        for (int r = 0; r < 4; ++r) a[r] += os[r][e] * w;
      }
      const float bv_ = bm[c];
      const int i0 = row0 & 511;
      #pragma unroll
      for (int r = 0; r < 4; ++r) {
        const float v = a[r] + bv_;
        if (m == 0)      qout[(size_t)(row0 + r) * D + c] = v;
        else if (m == 1) koutT[(size_t)b * D * N + (size_t)c * N + i0 + r] = v;
        else             vout[(size_t)(row0 + r) * D + c] = v;
      }
    }
  }
}

// ---------------------------------------------------------------------------
extern "C" void kernel_launch(void* const* d_in, const int* in_sizes, int n_in,
                              void* d_out, int out_size, void* d_ws, size_t ws_size,
                              hipStream_t stream) {
  // ws layout (4-byte units)
  int*   flags = (int*)d_ws;                 // [0]=isbf16 [1]=mask bytes/elem
  int*   mbuf  = flags + 16;                 // 1024 ints
  float* xbuf  = (float*)d_ws + 1040;        // 1024*128
  float* q0    = xbuf + NROW * D;
  float* k0T   = q0 + NROW * D;
  float* v0    = k0T + NROW * D;
  float* q1    = v0 + NROW * D;
  float* k1T   = q1 + NROW * D;
  float* v1    = k1T + NROW * D;
  float* W     = v1 + NROW * D;              // W_TOTAL floats

  NormArgs na;
  {
    int off = 0;
    for (int i = 0; i < NT; ++i) {
      na.s[i] = d_in[i + 1];
      na.d[i] = W + off;
      na.c[i] = CNT[i];
      off += CNT[i];
    }
  }
  const int* agent_id = (const int*)d_in[30];

  k_detect<<<1, 256, 0, stream>>>(d_in[9] /*bn_v*/, d_in[29] /*mask*/, flags, mbuf);
  k_norm<<<dim3(64, NT), 256, 0, stream>>>(na, flags);
  k_relq<<<NROW / 4, 512, 0, stream>>>(d_in[0], W, flags, mbuf, agent_id, xbuf,
                                       q0, k0T, v0);

  float* qs_[2] = {q0, q1};
  float* ks_[2] = {k0T, k1T};
  float* vs_[2] = {v0, v1};
  for (int l = 0; l < 3; ++l) {
    const int cur = l & 1, nxt = cur ^ 1;
    const bool last = (l == 2);
    k_layer<<<NROW / 4, 512, 0, stream>>>(
        qs_[cur], ks_[cur], vs_[cur],
        W + OFF_WO + l * D * D, W + OFF_BO + l * D,
        W + OFF_LN1G + l * D, W + OFF_LN1B + l * D,
        W + OFF_FW1 + l * D * F, W + OFF_FB1 + l * F,
        W + OFF_FW2 + l * F * D, W + OFF_FB2 + l * D,
        W + OFF_LN2G + l * D, W + OFF_LN2B + l * D,
        last ? (const float*)nullptr : W + OFF_WQ + (l + 1) * D * D,
        last ? (const float*)nullptr : W + OFF_BQ + (l + 1) * D,
        last ? (const float*)nullptr : W + OFF_WK + (l + 1) * D * D,
        last ? (const float*)nullptr : W + OFF_BK + (l + 1) * D,
        last ? (const float*)nullptr : W + OFF_WV + (l + 1) * D * D,
        last ? (const float*)nullptr : W + OFF_BV + (l + 1) * D,
        qs_[nxt], ks_[nxt], vs_[nxt],
        mbuf, xbuf, last ? (float*)d_out : (float*)nullptr);
  }
}

// Round 6
// 114.904 us; speedup vs baseline: 2.9373x; 1.1511x over previous
//
#include <hip/hip_runtime.h>
#include <hip/hip_bf16.h>

typedef unsigned short u16;
typedef unsigned int u32;
typedef unsigned char u8;

#define DEV __device__ __forceinline__

DEV float bf2f(u16 u) {
  union { u32 i; float f; } c; c.i = ((u32)u) << 16; return c.f;
}
DEV u16 f2bf(float f) {  // round-to-nearest-even
  union { float f; u32 i; } c; c.f = f;
  u32 r = c.i + 0x7FFFu + ((c.i >> 16) & 1u);
  return (u16)(r >> 16);
}
DEV float blo(u32 w) { union { u32 i; float f; } c; c.i = w << 16; return c.f; }
DEV float bhi(u32 w) { union { u32 i; float f; } c; c.i = w & 0xFFFF0000u; return c.f; }
DEV u32 pk2(float lo, float hi) { return (u32)f2bf(lo) | ((u32)f2bf(hi) << 16); }

static constexpr int B = 2, N = 512, D = 128, F = 512;
static constexpr int NROW = B * N;  // 1024
static constexpr float EPS = 1e-5f;
static constexpr float NEG = -1e9f;
static constexpr float SCALE = 0.08838834764831845f;  // 1/sqrt(128)

// ---- fp32 weight region offsets (order = d_in[1..28]) ---------------------
static constexpr int NT = 28;
static constexpr int CNT[NT] = {
  256, 128, 32768, 128, 16384, 128, 128, 128, 128, 16384, 128, 16384,
  49152, 384, 49152, 384, 49152, 384, 49152, 384, 384, 384, 384, 384,
  196608, 1536, 196608, 384};
#define OFF_PRE_W   0
#define OFF_PRE_B   256
#define OFF_PROJ_W  384
#define OFF_PROJ_B  33152
#define OFF_OUT_W1  33280
#define OFF_BN_G    49664
#define OFF_BN_B    49792
#define OFF_BN_M    49920
#define OFF_BN_V    50048
#define OFF_OUT_W2  50176
#define OFF_OUT_B2  66560
#define OFF_PE      66688
#define OFF_WQ      83072
#define OFF_BQ      132224
#define OFF_WK      132608
#define OFF_BK      181760
#define OFF_WV      182144
#define OFF_BV      231296
#define OFF_WO      231680
#define OFF_BO      280832
#define OFF_LN1G    281216
#define OFF_LN1B    281600
#define OFF_LN2G    281984
#define OFF_LN2B    282368
#define OFF_FW1     282752
#define OFF_FB1     479360
#define OFF_FW2     480896
#define OFF_FB2     677504
#define W_TOTAL     677888

// ---- packed-bf16 weight region (u32 units, pairs along K) -----------------
static constexpr int PB_PROJ = 0;       // 64x128   (proj_w[:128]+proj_w[128:])
static constexpr int PB_OW1  = 8192;    // 64x128
static constexpr int PB_OW2  = 16384;   // 64x128
static constexpr int PB_L0   = 24576;   // per-layer block base
static constexpr int PB_LSTR = 98304;   // per-layer stride
static constexpr int PB_WO   = 24576;   // within layer block
static constexpr int PB_FW1  = 32768;   // 64x512
static constexpr int PB_FW2  = 65536;   // 256x128
static constexpr int WB_TOTAL = PB_L0 + 3 * PB_LSTR;  // 319488 u32

struct NormArgs { const void* s[NT]; float* d[NT]; int c[NT]; };
struct PackEnt { int src, src2, dst, k, lgn; };
struct PackArgs { PackEnt e[21]; };

// ---------------------------------------------------------------------------
// k_detect: classify input encodings + normalize mask to int 0/1.
// ---------------------------------------------------------------------------
__global__ __launch_bounds__(256) void k_detect(
    const void* __restrict__ bnv, const void* __restrict__ maskp,
    int* __restrict__ flags, int* __restrict__ mbuf)
{
  const int t = threadIdx.x;
  __shared__ int s_nf, s_m4, s_m2;
  if (t == 0) { s_nf = 0; s_m4 = 0; s_m2 = 0; }
  __syncthreads();
  if (t < 64) {
    const u32 w = ((const u32*)bnv)[t];
    if (((w >> 8) & 0xFFu) != 0x3Fu || ((w >> 24) & 0xFFu) != 0x3Fu)
      atomicOr(&s_nf, 1);
  }
  {
    const u32 w = ((const u32*)maskp)[t];
    if (!(w == 0u || w == 1u || w == 0x3F800000u)) atomicOr(&s_m4, 1);
    if (!(w == 0u || w == 1u || w == 0x10000u || w == 0x10001u ||
          w == 0x3F80u || w == 0x3F800000u || w == 0x3F803F80u)) atomicOr(&s_m2, 1);
  }
  __syncthreads();
  const int isb  = s_nf ? 0 : 1;
  const int mode = (!s_m4) ? 4 : ((!s_m2) ? 2 : 1);  // bytes per mask element
  if (t == 0) { flags[0] = isb; flags[1] = mode; }
  #pragma unroll
  for (int k = 0; k < 4; ++k) {
    const int e = k * 256 + t;
    int v;
    if (mode == 4)      v = (((const u32*)maskp)[e] != 0u);
    else if (mode == 2) v = (((const u16*)maskp)[e] != 0);
    else                v = (((const u8*)maskp)[e]  != 0);
    mbuf[e] = v;
  }
}

// ---------------------------------------------------------------------------
// k_norm: convert all float tensors (fp32 or bf16 source) to fp32 in ws.
// ---------------------------------------------------------------------------
__global__ __launch_bounds__(256) void k_norm(NormArgs a, const int* __restrict__ flags) {
  const int ten = blockIdx.y;
  const int n = a.c[ten];
  const int isb = flags[0];
  const float* __restrict__ sf = (const float*)a.s[ten];
  const u16*   __restrict__ sh = (const u16*)a.s[ten];
  float* __restrict__ d = a.d[ten];
  for (int e = blockIdx.x * 256 + threadIdx.x; e < n; e += 64 * 256)
    d[e] = isb ? bf2f(sh[e]) : sf[e];
}

// ---------------------------------------------------------------------------
// k_pack: build K-pairwise-packed bf16 copies of the large weight matrices.
// Wb[dst + e2*N + c] = pack(Wsrc[2*e2][c], Wsrc[2*e2+1][c]) (+src2 if >=0)
// ---------------------------------------------------------------------------
__global__ __launch_bounds__(256) void k_pack(PackArgs pa,
    const float* __restrict__ W, u32* __restrict__ Wb)
{
  const PackEnt E = pa.e[blockIdx.y];
  const int Ncol = 1 << E.lgn;
  const int n = (E.k >> 1) << E.lgn;
  for (int idx = blockIdx.x * 256 + threadIdx.x; idx < n; idx += 32 * 256) {
    const int e2 = idx >> E.lgn;
    const int c  = idx & (Ncol - 1);
    const int r0 = (e2 << (E.lgn + 1)) + c;   // (2*e2)*N + c
    float f0 = W[E.src + r0], f1 = W[E.src + r0 + Ncol];
    if (E.src2 >= 0) { f0 += W[E.src2 + r0]; f1 += W[E.src2 + r0 + Ncol]; }
    Wb[E.dst + idx] = pk2(f0, f1);
  }
}

// ---------------------------------------------------------------------------
// k_relq: collapsed pairwise-relation chain + out-MLP + PE + QKV(layer 0).
// 4 rows/block, 256 blocks, 512 threads. Packed-bf16 weights.
// ---------------------------------------------------------------------------
__global__ __launch_bounds__(512) void k_relq(
    const void* __restrict__ relv, const float* __restrict__ W,
    const u32* __restrict__ Wb,
    const int* __restrict__ flags, const int* __restrict__ mbuf,
    const int* __restrict__ agent_id, float* __restrict__ xbuf,
    float* __restrict__ qb, u32* __restrict__ kbT, u32* __restrict__ vbT)
{
  const int t = threadIdx.x;            // 0..511
  const int row0 = blockIdx.x * 4;
  const int b = row0 >> 9;
  const int wid = t >> 6;

  __shared__ float pl[4][D], zl[4][D], rl[4][D], os[4][D];
  __shared__ float part[4][4][D];
  __shared__ float wred[8][9];
  __shared__ float sT0[4], sT1[4], sMt;

  // --- P1: masked sums over j of rel channels; Mtot ---
  float s0[4] = {0, 0, 0, 0}, s1[4] = {0, 0, 0, 0}, cnt;
  {
    const int j = t;
    const float m = (float)mbuf[b * N + j];
    cnt = m;
    if (flags[0]) {
      const u32* rel2 = (const u32*)relv;
      #pragma unroll
      for (int r = 0; r < 4; ++r) {
        const u32 u = rel2[(size_t)(row0 + r) * N + j];
        s0[r] += m * bf2f((u16)(u & 0xFFFFu));
        s1[r] += m * bf2f((u16)(u >> 16));
      }
    } else {
      const float2* relf = (const float2*)relv;
      #pragma unroll
      for (int r = 0; r < 4; ++r) {
        const float2 u = relf[(size_t)(row0 + r) * N + j];
        s0[r] += m * u.x; s1[r] += m * u.y;
      }
    }
  }
  #pragma unroll
  for (int o = 32; o > 0; o >>= 1) {
    #pragma unroll
    for (int r = 0; r < 4; ++r) {
      s0[r] += __shfl_xor(s0[r], o, 64);
      s1[r] += __shfl_xor(s1[r], o, 64);
    }
    cnt += __shfl_xor(cnt, o, 64);
  }
  if ((t & 63) == 0) {
    #pragma unroll
    for (int r = 0; r < 4; ++r) { wred[wid][r] = s0[r]; wred[wid][4 + r] = s1[r]; }
    wred[wid][8] = cnt;
  }
  __syncthreads();
  if (t < 4) {
    float a0 = 0, a1 = 0;
    #pragma unroll
    for (int w = 0; w < 8; ++w) { a0 += wred[w][t]; a1 += wred[w][4 + t]; }
    sT0[t] = a0; sT1[t] = a1;
  }
  if (t == 8) {
    float c = 0;
    #pragma unroll
    for (int w = 0; w < 8; ++w) c += wred[w][8];
    sMt = c;
  }
  __syncthreads();

  // --- P2: pooled ---
  {
    const int r = t >> 7, c = t & 127;
    const int mi = mbuf[row0 + r];
    pl[r][c] = mi ? (sT0[r] * W[OFF_PRE_W + c] + sT1[r] * W[OFF_PRE_W + D + c]) / sMt
                    + W[OFF_PRE_B + c]
                  : 0.f;
  }
  __syncthreads();

  // --- P3: z = pooled @ (P1+P2) + proj_b (masked) ---
  {
    const int d = t & 127, eq = t >> 7;
    float a[4] = {0, 0, 0, 0};
    #pragma unroll
    for (int ee = 0; ee < 16; ++ee) {
      const int e2 = eq * 16 + ee;
      const u32 w = Wb[PB_PROJ + e2 * 128 + d];
      const float wl = blo(w), wh = bhi(w);
      #pragma unroll
      for (int r = 0; r < 4; ++r)
        a[r] += pl[r][2 * e2] * wl + pl[r][2 * e2 + 1] * wh;
    }
    #pragma unroll
    for (int r = 0; r < 4; ++r) part[eq][r][d] = a[r];
  }
  __syncthreads();
  {
    const int r = t >> 7, d = t & 127;
    zl[r][d] = mbuf[row0 + r]
             ? part[0][r][d] + part[1][r][d] + part[2][r][d] + part[3][r][d]
               + W[OFF_PROJ_B + d]
             : 0.f;
  }
  __syncthreads();

  // --- P4: h = z @ out_w1; bn; relu ---
  {
    const int d = t & 127, eq = t >> 7;
    float a[4] = {0, 0, 0, 0};
    #pragma unroll
    for (int ee = 0; ee < 16; ++ee) {
      const int e2 = eq * 16 + ee;
      const u32 w = Wb[PB_OW1 + e2 * 128 + d];
      const float wl = blo(w), wh = bhi(w);
      #pragma unroll
      for (int r = 0; r < 4; ++r)
        a[r] += zl[r][2 * e2] * wl + zl[r][2 * e2 + 1] * wh;
    }
    #pragma unroll
    for (int r = 0; r < 4; ++r) part[eq][r][d] = a[r];
  }
  __syncthreads();
  {
    const int r = t >> 7, d = t & 127;
    const float h = part[0][r][d] + part[1][r][d] + part[2][r][d] + part[3][r][d];
    const float hb = (h - W[OFF_BN_M + d]) * __frsqrt_rn(W[OFF_BN_V + d] + EPS)
                     * W[OFF_BN_G + d] + W[OFF_BN_B + d];
    rl[r][d] = fmaxf(hb, 0.f);
  }
  __syncthreads();

  // --- P5: x0 = relu_h @ out_w2 + out_b2 + pe[agent_id] ---
  {
    const int d = t & 127, eq = t >> 7;
    float a[4] = {0, 0, 0, 0};
    #pragma unroll
    for (int ee = 0; ee < 16; ++ee) {
      const int e2 = eq * 16 + ee;
      const u32 w = Wb[PB_OW2 + e2 * 128 + d];
      const float wl = blo(w), wh = bhi(w);
      #pragma unroll
      for (int r = 0; r < 4; ++r)
        a[r] += rl[r][2 * e2] * wl + rl[r][2 * e2 + 1] * wh;
    }
    #pragma unroll
    for (int r = 0; r < 4; ++r) part[eq][r][d] = a[r];
  }
  __syncthreads();
  {
    const int r = t >> 7, d = t & 127;
    const int aid = agent_id[row0 + r];
    const float x0 = part[0][r][d] + part[1][r][d] + part[2][r][d] + part[3][r][d]
                   + W[OFF_OUT_B2 + d] + W[OFF_PE + aid * D + d];
    os[r][d] = x0;
    xbuf[(size_t)(row0 + r) * D + d] = x0;
  }
  __syncthreads();

  // --- P6: QKV layer 0 (packed weights; K^T and V stored packed bf16) ---
  {
    const int c = t & 127, m = t >> 7;
    if (m < 3) {
      const u32* Wp = Wb + PB_L0 + m * 8192;   // WQ / WK / WV of layer 0
      const float* bm = W + ((m == 0) ? OFF_BQ : (m == 1) ? OFF_BK : OFF_BV);
      float a[4] = {0, 0, 0, 0};
      #pragma unroll 8
      for (int e2 = 0; e2 < 64; ++e2) {
        const u32 w = Wp[e2 * 128 + c];
        const float wl = blo(w), wh = bhi(w);
        #pragma unroll
        for (int r = 0; r < 4; ++r)
          a[r] += os[r][2 * e2] * wl + os[r][2 * e2 + 1] * wh;
      }
      const float bv_ = bm[c];
      const int i0 = row0 & 511;
      if (m == 0) {
        #pragma unroll
        for (int r = 0; r < 4; ++r)
          qb[(size_t)(row0 + r) * D + c] = a[r] + bv_;
      } else if (m == 1) {
        #pragma unroll
        for (int r = 0; r < 4; ++r) {
          const float v = a[r] + bv_;
          const float ov = __shfl_xor(v, 1, 64);
          if ((c & 1) == 0)
            kbT[(size_t)b * 64 * N + (size_t)(c >> 1) * N + i0 + r] = pk2(v, ov);
        }
      } else {
        #pragma unroll
        for (int rp = 0; rp < 2; ++rp) {
          const float vlo = a[2 * rp] + bv_, vhi = a[2 * rp + 1] + bv_;
          vbT[(size_t)b * 256 * D + (size_t)((i0 >> 1) + rp) * D + c] = pk2(vlo, vhi);
        }
      }
    }
  }
}

// ---------------------------------------------------------------------------
// k_layer: fused attn + LN1 + FFN + LN2 [+ QKV(l+1)] for 4 rows/block.
// 256 blocks, 512 threads. Packed-bf16 weights and K^T/V buffers.
// ---------------------------------------------------------------------------
__global__ __launch_bounds__(512) void k_layer(
    const float* __restrict__ qin, const u32* __restrict__ kinT, const u32* __restrict__ vinT,
    const float* __restrict__ W, const u32* __restrict__ Wb, const int l, const int last,
    float* __restrict__ qout, u32* __restrict__ koutT, u32* __restrict__ voutT,
    const int* __restrict__ mbuf, float* __restrict__ xbuf, float* __restrict__ outp)
{
  const int t = threadIdx.x;            // 0..511
  const int row0 = blockIdx.x * 4;
  const int b = row0 >> 9;
  const int wid = t >> 6;

  const u32* WOp = Wb + PB_L0 + l * PB_LSTR + PB_WO;
  const u32* W1p = Wb + PB_L0 + l * PB_LSTR + PB_FW1;
  const u32* W2p = Wb + PB_L0 + l * PB_LSTR + PB_FW2;
  const float* bo  = W + OFF_BO  + l * D;
  const float* g1  = W + OFF_LN1G + l * D;
  const float* b1  = W + OFF_LN1B + l * D;
  const float* fb1 = W + OFF_FB1 + l * F;
  const float* fb2 = W + OFF_FB2 + l * D;
  const float* g2  = W + OFF_LN2G + l * D;
  const float* b2v = W + OFF_LN2B + l * D;

  __shared__ float qs[4][D];
  __shared__ float p[4][N];
  __shared__ float part[4][4][D];
  __shared__ float os[4][D];
  __shared__ float xs[4][D];
  __shared__ float hs[4][F];
  __shared__ float den[4];

  // A: load Q rows
  {
    const int r = t >> 7, d = t & 127;
    qs[r][d] = qin[(size_t)(row0 + r) * D + d];
  }
  __syncthreads();

  // B: scores — thread t owns key j=t; packed K^T
  {
    const u32* kcol = kinT + (size_t)b * 64 * N + t;
    float a[4] = {0, 0, 0, 0};
    #pragma unroll 8
    for (int e2 = 0; e2 < 64; ++e2) {
      const u32 w = kcol[e2 * N];
      const float wl = blo(w), wh = bhi(w);
      #pragma unroll
      for (int r = 0; r < 4; ++r)
        a[r] += qs[r][2 * e2] * wl + qs[r][2 * e2 + 1] * wh;
    }
    const float bias = mbuf[b * N + t] ? 0.f : NEG;
    #pragma unroll
    for (int r = 0; r < 4; ++r) p[r][t] = a[r] * SCALE + bias;
  }
  __syncthreads();

  // C: softmax — wave w handles row w (waves 4..7 idle)
  if (wid < 4) {
    const int r = wid, lane = t & 63;
    float pv[8];
    float mx = -1e30f;
    #pragma unroll
    for (int k = 0; k < 8; ++k) { pv[k] = p[r][lane + 64 * k]; mx = fmaxf(mx, pv[k]); }
    #pragma unroll
    for (int o = 32; o > 0; o >>= 1) mx = fmaxf(mx, __shfl_xor(mx, o, 64));
    float sum = 0.f;
    #pragma unroll
    for (int k = 0; k < 8; ++k) { pv[k] = __expf(pv[k] - mx); sum += pv[k]; }
    #pragma unroll
    for (int o = 32; o > 0; o >>= 1) sum += __shfl_xor(sum, o, 64);
    #pragma unroll
    for (int k = 0; k < 8; ++k) p[r][lane + 64 * k] = pv[k];
    if (lane == 0) den[r] = sum;
  }
  __syncthreads();

  // D: AV — d = t&127, key-quarter = t>>7; packed V (row pairs)
  {
    const int d = t & 127, q4 = t >> 7;
    const u32* vp = vinT + (size_t)b * 256 * D + (size_t)(q4 * 64) * D + d;
    float a[4] = {0, 0, 0, 0};
    #pragma unroll 8
    for (int a2 = 0; a2 < 64; ++a2) {
      const u32 w = vp[a2 * D];
      const float vl = blo(w), vh = bhi(w);
      #pragma unroll
      for (int r = 0; r < 4; ++r)
        a[r] += p[r][q4 * 128 + 2 * a2] * vl + p[r][q4 * 128 + 2 * a2 + 1] * vh;
    }
    #pragma unroll
    for (int r = 0; r < 4; ++r) part[q4][r][d] = a[r];
  }
  __syncthreads();
  {
    const int r = t >> 7, d = t & 127;
    os[r][d] = (part[0][r][d] + part[1][r][d] + part[2][r][d] + part[3][r][d]) / den[r];
  }
  __syncthreads();

  // E: WO — d = t&127, e-quarter = t>>7; packed
  {
    const int d = t & 127, eq = t >> 7;
    float a[4] = {0, 0, 0, 0};
    #pragma unroll
    for (int ee = 0; ee < 16; ++ee) {
      const int e2 = eq * 16 + ee;
      const u32 w = WOp[e2 * 128 + d];
      const float wl = blo(w), wh = bhi(w);
      #pragma unroll
      for (int r = 0; r < 4; ++r)
        a[r] += os[r][2 * e2] * wl + os[r][2 * e2 + 1] * wh;
    }
    #pragma unroll
    for (int r = 0; r < 4; ++r) part[eq][r][d] = a[r];
  }
  __syncthreads();

  // F: residual + LN1 — wave w handles row w
  if (wid < 4) {
    const int r = wid, lane = t & 63;
    float tv[2];
    #pragma unroll
    for (int k = 0; k < 2; ++k) {
      const int d = lane + 64 * k;
      tv[k] = part[0][r][d] + part[1][r][d] + part[2][r][d] + part[3][r][d]
            + bo[d] + xbuf[(size_t)(row0 + r) * D + d];
    }
    float s = tv[0] + tv[1], sq = tv[0] * tv[0] + tv[1] * tv[1];
    #pragma unroll
    for (int o = 32; o > 0; o >>= 1) { s += __shfl_xor(s, o, 64); sq += __shfl_xor(sq, o, 64); }
    const float mean = s * (1.f / 128.f);
    const float var  = sq * (1.f / 128.f) - mean * mean;
    const float rstd = __frsqrt_rn(var + EPS);
    #pragma unroll
    for (int k = 0; k < 2; ++k) {
      const int d = lane + 64 * k;
      xs[r][d] = (tv[k] - mean) * rstd * g1[d] + b1[d];
    }
  }
  __syncthreads();

  // G: FFN1 — thread t owns f=t; packed
  {
    float a[4] = {0, 0, 0, 0};
    #pragma unroll 8
    for (int e2 = 0; e2 < 64; ++e2) {
      const u32 w = W1p[e2 * F + t];
      const float wl = blo(w), wh = bhi(w);
      #pragma unroll
      for (int r = 0; r < 4; ++r)
        a[r] += xs[r][2 * e2] * wl + xs[r][2 * e2 + 1] * wh;
    }
    const float bb = fb1[t];
    #pragma unroll
    for (int r = 0; r < 4; ++r) hs[r][t] = fmaxf(a[r] + bb, 0.f);
  }
  __syncthreads();

  // H: FFN2 — d = t&127, f-quarter = t>>7; packed
  {
    const int d = t & 127, fq = t >> 7;
    float a[4] = {0, 0, 0, 0};
    #pragma unroll 8
    for (int ff = 0; ff < 64; ++ff) {
      const int f2 = fq * 64 + ff;
      const u32 w = W2p[f2 * 128 + d];
      const float wl = blo(w), wh = bhi(w);
      #pragma unroll
      for (int r = 0; r < 4; ++r)
        a[r] += hs[r][2 * f2] * wl + hs[r][2 * f2 + 1] * wh;
    }
    #pragma unroll
    for (int r = 0; r < 4; ++r) part[fq][r][d] = a[r];
  }
  __syncthreads();

  // I: residual + LN2 — wave w handles row w; write to os/xbuf (+outp)
  if (wid < 4) {
    const int r = wid, lane = t & 63;
    float tv[2];
    #pragma unroll
    for (int k = 0; k < 2; ++k) {
      const int d = lane + 64 * k;
      tv[k] = part[0][r][d] + part[1][r][d] + part[2][r][d] + part[3][r][d]
            + fb2[d] + xs[r][d];
    }
    float s = tv[0] + tv[1], sq = tv[0] * tv[0] + tv[1] * tv[1];
    #pragma unroll
    for (int o = 32; o > 0; o >>= 1) { s += __shfl_xor(s, o, 64); sq += __shfl_xor(sq, o, 64); }
    const float mean = s * (1.f / 128.f);
    const float var  = sq * (1.f / 128.f) - mean * mean;
    const float rstd = __frsqrt_rn(var + EPS);
    #pragma unroll
    for (int k = 0; k < 2; ++k) {
      const int d = lane + 64 * k;
      const float xn = (tv[k] - mean) * rstd * g2[d] + b2v[d];
      os[r][d] = xn;
      xbuf[(size_t)(row0 + r) * D + d] = xn;
      if (outp) outp[(size_t)(row0 + r) * D + d] = xn;
    }
  }
  __syncthreads();

  // J: QKV for next layer (packed weights; packed K^T/V outputs)
  if (!last) {
    const int c = t & 127, m = t >> 7;
    if (m < 3) {
      const u32* Wp = Wb + PB_L0 + (l + 1) * PB_LSTR + m * 8192;
      const float* bm = W + ((m == 0) ? OFF_BQ : (m == 1) ? OFF_BK : OFF_BV) + (l + 1) * D;
      float a[4] = {0, 0, 0, 0};
      #pragma unroll 8
      for (int e2 = 0; e2 < 64; ++e2) {
        const u32 w = Wp[e2 * 128 + c];
        const float wl = blo(w), wh = bhi(w);
        #pragma unroll
        for (int r = 0; r < 4; ++r)
          a[r] += os[r][2 * e2] * wl + os[r][2 * e2 + 1] * wh;
      }
      const float bv_ = bm[c];
      const int i0 = row0 & 511;
      if (m == 0) {
        #pragma unroll
        for (int r = 0; r < 4; ++r)
          qout[(size_t)(row0 + r) * D + c] = a[r] + bv_;
      } else if (m == 1) {
        #pragma unroll
        for (int r = 0; r < 4; ++r) {
          const float v = a[r] + bv_;
          const float ov = __shfl_xor(v, 1, 64);
          if ((c & 1) == 0)
            koutT[(size_t)b * 64 * N + (size_t)(c >> 1) * N + i0 + r] = pk2(v, ov);
        }
      } else {
        #pragma unroll
        for (int rp = 0; rp < 2; ++rp) {
          const float vlo = a[2 * rp] + bv_, vhi = a[2 * rp + 1] + bv_;
          voutT[(size_t)b * 256 * D + (size_t)((i0 >> 1) + rp) * D + c] = pk2(vlo, vhi);
        }
      }
    }
  }
}

// ---------------------------------------------------------------------------
extern "C" void kernel_launch(void* const* d_in, const int* in_sizes, int n_in,
                              void* d_out, int out_size, void* d_ws, size_t ws_size,
                              hipStream_t stream) {
  // ws layout (4-byte units)
  int*   flags = (int*)d_ws;                 // [0]=isbf16 [1]=mask bytes/elem
  int*   mbuf  = flags + 16;                 // 1024 ints
  float* xbuf  = (float*)d_ws + 1040;        // 1024*128
  float* q0    = xbuf + NROW * D;
  float* q1    = q0 + NROW * D;
  u32*   kT0   = (u32*)(q1 + NROW * D);      // [B][64][512] u32
  u32*   kT1   = kT0 + 65536;
  u32*   vT0   = kT1 + 65536;                // [B][256][128] u32
  u32*   vT1   = vT0 + 65536;
  float* W     = (float*)(vT1 + 65536);      // W_TOTAL floats
  u32*   Wb    = (u32*)(W + W_TOTAL);        // WB_TOTAL u32

  NormArgs na;
  {
    int off = 0;
    for (int i = 0; i < NT; ++i) {
      na.s[i] = d_in[i + 1];
      na.d[i] = W + off;
      na.c[i] = CNT[i];
      off += CNT[i];
    }
  }
  PackArgs pa;
  {
    pa.e[0] = {OFF_PROJ_W, OFF_PROJ_W + 128 * 128, PB_PROJ, 128, 7};
    pa.e[1] = {OFF_OUT_W1, -1, PB_OW1, 128, 7};
    pa.e[2] = {OFF_OUT_W2, -1, PB_OW2, 128, 7};
    for (int l = 0; l < 3; ++l) {
      const int base = PB_L0 + l * PB_LSTR;
      pa.e[3 + 6 * l + 0] = {OFF_WQ + l * 16384, -1, base,          128, 7};
      pa.e[3 + 6 * l + 1] = {OFF_WK + l * 16384, -1, base + 8192,   128, 7};
      pa.e[3 + 6 * l + 2] = {OFF_WV + l * 16384, -1, base + 16384,  128, 7};
      pa.e[3 + 6 * l + 3] = {OFF_WO + l * 16384, -1, base + PB_WO,  128, 7};
      pa.e[3 + 6 * l + 4] = {OFF_FW1 + l * 65536, -1, base + PB_FW1, 128, 9};
      pa.e[3 + 6 * l + 5] = {OFF_FW2 + l * 65536, -1, base + PB_FW2, 512, 7};
    }
  }
  const int* agent_id = (const int*)d_in[30];

  k_detect<<<1, 256, 0, stream>>>(d_in[9] /*bn_v*/, d_in[29] /*mask*/, flags, mbuf);
  k_norm<<<dim3(64, NT), 256, 0, stream>>>(na, flags);
  k_pack<<<dim3(32, 21), 256, 0, stream>>>(pa, W, Wb);
  k_relq<<<NROW / 4, 512, 0, stream>>>(d_in[0], W, Wb, flags, mbuf, agent_id, xbuf,
                                       q0, kT0, vT0);

  float* qs_[2] = {q0, q1};
  u32*   ks_[2] = {kT0, kT1};
  u32*   vs_[2] = {vT0, vT1};
  for (int l = 0; l < 3; ++l) {
    const int cur = l & 1, nxt = cur ^ 1;
    const int last = (l == 2);
    k_layer<<<NROW / 4, 512, 0, stream>>>(
        qs_[cur], ks_[cur], vs_[cur],
        W, Wb, l, last,
        qs_[nxt], ks_[nxt], vs_[nxt],
        mbuf, xbuf, last ? (float*)d_out : (float*)nullptr);
  }
}

// Round 7
// 89.684 us; speedup vs baseline: 3.7633x; 1.2812x over previous
//
#include <hip/hip_runtime.h>
#include <hip/hip_bf16.h>

typedef unsigned short u16;
typedef unsigned int u32;
typedef unsigned char u8;

#define DEV __device__ __forceinline__

DEV float bf2f(u16 u) { union { u32 i; float f; } c; c.i = ((u32)u) << 16; return c.f; }
DEV u16 f2bf(float f) {  // round-to-nearest-even
  union { float f; u32 i; } c; c.f = f;
  u32 r = c.i + 0x7FFFu + ((c.i >> 16) & 1u);
  return (u16)(r >> 16);
}
DEV float blo(u32 w) { union { u32 i; float f; } c; c.i = w << 16; return c.f; }
DEV float bhi(u32 w) { union { u32 i; float f; } c; c.i = w & 0xFFFF0000u; return c.f; }
DEV u32 pk2(float lo, float hi) { return (u32)f2bf(lo) | ((u32)f2bf(hi) << 16); }
DEV float rdsrc(const void* p, int e, int isb) {
  return isb ? bf2f(((const u16*)p)[e]) : ((const float*)p)[e];
}

// 32 FMAs: one uint4 (8 bf16 along K) against SRC[0..3][E0..E0+7]
#define F8(W4, E0, SRC, A) do { \
  u32 _w = (W4).x; float _l = blo(_w), _h = bhi(_w); \
  A[0] += SRC[0][(E0)+0]*_l + SRC[0][(E0)+1]*_h; \
  A[1] += SRC[1][(E0)+0]*_l + SRC[1][(E0)+1]*_h; \
  A[2] += SRC[2][(E0)+0]*_l + SRC[2][(E0)+1]*_h; \
  A[3] += SRC[3][(E0)+0]*_l + SRC[3][(E0)+1]*_h; \
  _w = (W4).y; _l = blo(_w); _h = bhi(_w); \
  A[0] += SRC[0][(E0)+2]*_l + SRC[0][(E0)+3]*_h; \
  A[1] += SRC[1][(E0)+2]*_l + SRC[1][(E0)+3]*_h; \
  A[2] += SRC[2][(E0)+2]*_l + SRC[2][(E0)+3]*_h; \
  A[3] += SRC[3][(E0)+2]*_l + SRC[3][(E0)+3]*_h; \
  _w = (W4).z; _l = blo(_w); _h = bhi(_w); \
  A[0] += SRC[0][(E0)+4]*_l + SRC[0][(E0)+5]*_h; \
  A[1] += SRC[1][(E0)+4]*_l + SRC[1][(E0)+5]*_h; \
  A[2] += SRC[2][(E0)+4]*_l + SRC[2][(E0)+5]*_h; \
  A[3] += SRC[3][(E0)+4]*_l + SRC[3][(E0)+5]*_h; \
  _w = (W4).w; _l = blo(_w); _h = bhi(_w); \
  A[0] += SRC[0][(E0)+6]*_l + SRC[0][(E0)+7]*_h; \
  A[1] += SRC[1][(E0)+6]*_l + SRC[1][(E0)+7]*_h; \
  A[2] += SRC[2][(E0)+6]*_l + SRC[2][(E0)+7]*_h; \
  A[3] += SRC[3][(E0)+6]*_l + SRC[3][(E0)+7]*_h; \
} while (0)

static constexpr int B = 2, N = 512, D = 128, F = 512;
static constexpr int NROW = B * N;  // 1024
static constexpr float EPS = 1e-5f;
static constexpr float NEG = -1e9f;
static constexpr float SCALE = 0.08838834764831845f;  // 1/sqrt(128)

// ---- fp32 small-weight region offsets (subset populated) ------------------
#define OFF_PRE_W   0
#define OFF_PRE_B   256
#define OFF_PROJ_B  33152
#define OFF_BN_G    49664
#define OFF_BN_B    49792
#define OFF_BN_M    49920
#define OFF_BN_V    50048
#define OFF_OUT_B2  66560
#define OFF_PE      66688
#define OFF_BQ      132224
#define OFF_BK      181760
#define OFF_BV      231296
#define OFF_BO      280832
#define OFF_LN1G    281216
#define OFF_LN1B    281600
#define OFF_LN2G    281984
#define OFF_LN2B    282368
#define OFF_FB1     479360
#define OFF_FB2     677504
#define W_TOTAL     677888

// ---- packed-bf16 weight region (u32 units; interior = uint4 of 8 K-elems) -
static constexpr int PB_PROJ = 0;       // K=128, N=128
static constexpr int PB_OW1  = 8192;
static constexpr int PB_OW2  = 16384;
static constexpr int PB_L0   = 24576;
static constexpr int PB_LSTR = 98304;
static constexpr int PB_WO   = 24576;   // within layer block
static constexpr int PB_FW1  = 32768;   // K=128, N=512
static constexpr int PB_FW2  = 65536;   // K=512, N=128
static constexpr int PTOT    = 79872;   // total uint4 pack entries

struct NEnt { const void* s; int off, n; };
struct PEnt { const void* s1; const void* s2; int o1, o2, dst, lgn, cum; };
struct PrepArgs { NEnt nrm[19]; PEnt pk[21]; };

// ---------------------------------------------------------------------------
// k_prep: (a) blocks 0..15 norm small tensors to fp32 W; (b) blocks 16..142
// build packed-bf16 uint4 weights from d_in directly; (c) block 143 writes
// flags + normalized mask. Every block self-detects fp32-vs-bf16 from bn_v.
// ---------------------------------------------------------------------------
__global__ __launch_bounds__(256) void k_prep(PrepArgs pa,
    const void* __restrict__ bnv, const void* __restrict__ maskp,
    int* __restrict__ flags, int* __restrict__ mbuf,
    float* __restrict__ W, u32* __restrict__ Wb)
{
  const int t = threadIdx.x, bid = blockIdx.x;
  __shared__ int s_nb, s_m4, s_m2;
  if (t == 0) { s_nb = 0; s_m4 = 0; s_m2 = 0; }
  __syncthreads();
  if (t < 64) {
    const u32 w = ((const u32*)bnv)[t];
    if (((w >> 8) & 0xFFu) != 0x3Fu || ((w >> 24) & 0xFFu) != 0x3Fu)
      atomicOr(&s_nb, 1);
  }
  __syncthreads();
  const int isb = s_nb ? 0 : 1;

  if (bid < 16) {
    for (int ten = 0; ten < 19; ++ten) {
      const NEnt E = pa.nrm[ten];
      for (int e = bid * 256 + t; e < E.n; e += 16 * 256)
        W[E.off + e] = rdsrc(E.s, e, isb);
    }
  } else if (bid < 143) {
    for (int g = (bid - 16) * 256 + t; g < PTOT; g += 127 * 256) {
      int ei = 0;
      #pragma unroll
      for (int k = 1; k < 21; ++k) if (g >= pa.pk[k].cum) ei = k;
      const PEnt E = pa.pk[ei];
      const int li = g - E.cum;
      const int e8 = li >> E.lgn, c = li & ((1 << E.lgn) - 1);
      float f[8];
      #pragma unroll
      for (int i = 0; i < 8; ++i) {
        const int si = ((e8 * 8 + i) << E.lgn) + c;
        f[i] = rdsrc(E.s1, E.o1 + si, isb);
        if (E.s2) f[i] += rdsrc(E.s2, E.o2 + si, isb);
      }
      uint4 w;
      w.x = pk2(f[0], f[1]); w.y = pk2(f[2], f[3]);
      w.z = pk2(f[4], f[5]); w.w = pk2(f[6], f[7]);
      ((uint4*)(Wb + E.dst))[li] = w;
    }
  } else {
    {
      const u32 w = ((const u32*)maskp)[t];
      if (!(w == 0u || w == 1u || w == 0x3F800000u)) atomicOr(&s_m4, 1);
      if (!(w == 0u || w == 1u || w == 0x10000u || w == 0x10001u ||
            w == 0x3F80u || w == 0x3F800000u || w == 0x3F803F80u)) atomicOr(&s_m2, 1);
    }
    __syncthreads();
    const int mode = (!s_m4) ? 4 : ((!s_m2) ? 2 : 1);
    if (t == 0) { flags[0] = isb; flags[1] = mode; }
    #pragma unroll
    for (int k = 0; k < 4; ++k) {
      const int e = k * 256 + t;
      int v;
      if (mode == 4)      v = (((const u32*)maskp)[e] != 0u);
      else if (mode == 2) v = (((const u16*)maskp)[e] != 0);
      else                v = (((const u8*)maskp)[e]  != 0);
      mbuf[e] = v;
    }
  }
}

// ---------------------------------------------------------------------------
// k_relq: collapsed pairwise chain + out-MLP + PE + QKV(layer 0).
// 4 rows/block, 256 blocks, 512 threads, uint4 packed weights.
// ---------------------------------------------------------------------------
__global__ __launch_bounds__(512) void k_relq(
    const void* __restrict__ relv, const float* __restrict__ W,
    const u32* __restrict__ Wb,
    const int* __restrict__ flags, const int* __restrict__ mbuf,
    const int* __restrict__ agent_id, float* __restrict__ xbuf,
    float* __restrict__ qb, u32* __restrict__ kbT, u32* __restrict__ vbT)
{
  const int t = threadIdx.x;            // 0..511
  const int row0 = blockIdx.x * 4;
  const int b = row0 >> 9;
  const int wid = t >> 6;

  __shared__ float pl[4][D], zl[4][D], rl[4][D], os[4][D];
  __shared__ float part[4][4][D];
  __shared__ float wred[8][9];
  __shared__ float sT0[4], sT1[4], sMt;

  // --- P1: masked sums over j of rel channels; Mtot ---
  float s0[4] = {0, 0, 0, 0}, s1[4] = {0, 0, 0, 0}, cnt;
  {
    const int j = t;
    const float m = (float)mbuf[b * N + j];
    cnt = m;
    if (flags[0]) {
      const u32* rel2 = (const u32*)relv;
      #pragma unroll
      for (int r = 0; r < 4; ++r) {
        const u32 u = rel2[(size_t)(row0 + r) * N + j];
        s0[r] += m * bf2f((u16)(u & 0xFFFFu));
        s1[r] += m * bf2f((u16)(u >> 16));
      }
    } else {
      const float2* relf = (const float2*)relv;
      #pragma unroll
      for (int r = 0; r < 4; ++r) {
        const float2 u = relf[(size_t)(row0 + r) * N + j];
        s0[r] += m * u.x; s1[r] += m * u.y;
      }
    }
  }
  #pragma unroll
  for (int o = 32; o > 0; o >>= 1) {
    #pragma unroll
    for (int r = 0; r < 4; ++r) {
      s0[r] += __shfl_xor(s0[r], o, 64);
      s1[r] += __shfl_xor(s1[r], o, 64);
    }
    cnt += __shfl_xor(cnt, o, 64);
  }
  if ((t & 63) == 0) {
    #pragma unroll
    for (int r = 0; r < 4; ++r) { wred[wid][r] = s0[r]; wred[wid][4 + r] = s1[r]; }
    wred[wid][8] = cnt;
  }
  __syncthreads();
  if (t < 4) {
    float a0 = 0, a1 = 0;
    #pragma unroll
    for (int w = 0; w < 8; ++w) { a0 += wred[w][t]; a1 += wred[w][4 + t]; }
    sT0[t] = a0; sT1[t] = a1;
  }
  if (t == 8) {
    float c = 0;
    #pragma unroll
    for (int w = 0; w < 8; ++w) c += wred[w][8];
    sMt = c;
  }
  __syncthreads();

  // --- P2: pooled ---
  {
    const int r = t >> 7, c = t & 127;
    const int mi = mbuf[row0 + r];
    pl[r][c] = mi ? (sT0[r] * W[OFF_PRE_W + c] + sT1[r] * W[OFF_PRE_W + D + c]) / sMt
                    + W[OFF_PRE_B + c]
                  : 0.f;
  }
  __syncthreads();

  // --- P3: z = pooled @ (P1+P2) + proj_b (masked) ---
  {
    const int d = t & 127, eq = t >> 7;
    const uint4* Wp = (const uint4*)(Wb + PB_PROJ);
    float a[4] = {0, 0, 0, 0};
    #pragma unroll
    for (int ee = 0; ee < 4; ++ee) {
      const int e8 = eq * 4 + ee;
      uint4 w = Wp[(size_t)e8 * 128 + d];
      F8(w, 8 * e8, pl, a);
    }
    #pragma unroll
    for (int r = 0; r < 4; ++r) part[eq][r][d] = a[r];
  }
  __syncthreads();
  {
    const int r = t >> 7, d = t & 127;
    zl[r][d] = mbuf[row0 + r]
             ? part[0][r][d] + part[1][r][d] + part[2][r][d] + part[3][r][d]
               + W[OFF_PROJ_B + d]
             : 0.f;
  }
  __syncthreads();

  // --- P4: h = z @ out_w1; bn; relu ---
  {
    const int d = t & 127, eq = t >> 7;
    const uint4* Wp = (const uint4*)(Wb + PB_OW1);
    float a[4] = {0, 0, 0, 0};
    #pragma unroll
    for (int ee = 0; ee < 4; ++ee) {
      const int e8 = eq * 4 + ee;
      uint4 w = Wp[(size_t)e8 * 128 + d];
      F8(w, 8 * e8, zl, a);
    }
    #pragma unroll
    for (int r = 0; r < 4; ++r) part[eq][r][d] = a[r];
  }
  __syncthreads();
  {
    const int r = t >> 7, d = t & 127;
    const float h = part[0][r][d] + part[1][r][d] + part[2][r][d] + part[3][r][d];
    const float hb = (h - W[OFF_BN_M + d]) * __frsqrt_rn(W[OFF_BN_V + d] + EPS)
                     * W[OFF_BN_G + d] + W[OFF_BN_B + d];
    rl[r][d] = fmaxf(hb, 0.f);
  }
  __syncthreads();

  // --- P5: x0 = relu_h @ out_w2 + out_b2 + pe[agent_id] ---
  {
    const int d = t & 127, eq = t >> 7;
    const uint4* Wp = (const uint4*)(Wb + PB_OW2);
    float a[4] = {0, 0, 0, 0};
    #pragma unroll
    for (int ee = 0; ee < 4; ++ee) {
      const int e8 = eq * 4 + ee;
      uint4 w = Wp[(size_t)e8 * 128 + d];
      F8(w, 8 * e8, rl, a);
    }
    #pragma unroll
    for (int r = 0; r < 4; ++r) part[eq][r][d] = a[r];
  }
  __syncthreads();
  {
    const int r = t >> 7, d = t & 127;
    const int aid = agent_id[row0 + r];
    const float x0 = part[0][r][d] + part[1][r][d] + part[2][r][d] + part[3][r][d]
                   + W[OFF_OUT_B2 + d] + W[OFF_PE + aid * D + d];
    os[r][d] = x0;
    xbuf[(size_t)(row0 + r) * D + d] = x0;
  }
  __syncthreads();

  // --- P6: QKV layer 0 ---
  {
    const int c = t & 127, m = t >> 7;
    if (m < 3) {
      const uint4* Wp = (const uint4*)(Wb + PB_L0 + m * 8192);
      const float* bm = W + ((m == 0) ? OFF_BQ : (m == 1) ? OFF_BK : OFF_BV);
      float a[4] = {0, 0, 0, 0};
      #pragma unroll
      for (int e8 = 0; e8 < 16; ++e8) {
        uint4 w = Wp[(size_t)e8 * 128 + c];
        F8(w, 8 * e8, os, a);
      }
      const float bv_ = bm[c];
      if (m == 0) {
        #pragma unroll
        for (int r = 0; r < 4; ++r) qb[(size_t)(row0 + r) * D + c] = a[r] + bv_;
      } else if (m == 1) {
        #pragma unroll
        for (int r = 0; r < 4; ++r) part[0][r][c] = a[r] + bv_;
      } else {
        #pragma unroll
        for (int r = 0; r < 4; ++r) part[1][r][c] = a[r] + bv_;
      }
    }
  }
  __syncthreads();
  if (t < 64) {   // packed K^T write: [b][e8][j] uint4
    const int r = t >> 4, e8 = t & 15;
    const float* ks = part[0][r];
    uint4 w;
    w.x = pk2(ks[8 * e8 + 0], ks[8 * e8 + 1]);
    w.y = pk2(ks[8 * e8 + 2], ks[8 * e8 + 3]);
    w.z = pk2(ks[8 * e8 + 4], ks[8 * e8 + 5]);
    w.w = pk2(ks[8 * e8 + 6], ks[8 * e8 + 7]);
    ((uint4*)kbT)[((size_t)b * 16 + e8) * 512 + (row0 & 511) + r] = w;
  }
  if (t < 128) {  // packed V write: [b][j8][d] uint4 (half per block)
    const int i0 = row0 & 511, j8 = i0 >> 3, h = (i0 >> 2) & 1;
    uint2 w;
    w.x = pk2(part[1][0][t], part[1][1][t]);
    w.y = pk2(part[1][2][t], part[1][3][t]);
    *(uint2*)(vbT + (((size_t)b * 64 + j8) * 128 + t) * 4 + 2 * h) = w;
  }
}

// ---------------------------------------------------------------------------
// k_layer: fused attn + LN1 + FFN + LN2 [+ QKV(l+1)] for 4 rows/block.
// 256 blocks, 512 threads. All streamed operands are uint4-packed bf16.
// ---------------------------------------------------------------------------
__global__ __launch_bounds__(512) void k_layer(
    const float* __restrict__ qin, const u32* __restrict__ kinT, const u32* __restrict__ vinT,
    const float* __restrict__ W, const u32* __restrict__ Wb, const int l, const int last,
    float* __restrict__ qout, u32* __restrict__ koutT, u32* __restrict__ voutT,
    const int* __restrict__ mbuf, float* __restrict__ xbuf, float* __restrict__ outp)
{
  const int t = threadIdx.x;            // 0..511
  const int row0 = blockIdx.x * 4;
  const int b = row0 >> 9;
  const int wid = t >> 6;

  const uint4* WOp = (const uint4*)(Wb + PB_L0 + l * PB_LSTR + PB_WO);
  const uint4* W1p = (const uint4*)(Wb + PB_L0 + l * PB_LSTR + PB_FW1);
  const uint4* W2p = (const uint4*)(Wb + PB_L0 + l * PB_LSTR + PB_FW2);
  const float* bo  = W + OFF_BO  + l * D;
  const float* g1  = W + OFF_LN1G + l * D;
  const float* b1  = W + OFF_LN1B + l * D;
  const float* fb1 = W + OFF_FB1 + l * F;
  const float* fb2 = W + OFF_FB2 + l * D;
  const float* g2  = W + OFF_LN2G + l * D;
  const float* b2v = W + OFF_LN2B + l * D;

  __shared__ float qs[4][D];
  __shared__ float p[4][N];
  __shared__ float part[4][4][D];
  __shared__ float os[4][D];
  __shared__ float xs[4][D];
  __shared__ float hs[4][F];
  __shared__ float den[4];

  // A: load Q rows, pre-scaled
  {
    const int r = t >> 7, d = t & 127;
    qs[r][d] = qin[(size_t)(row0 + r) * D + d] * SCALE;
  }
  __syncthreads();

  // B: scores — thread t owns key j=t; packed K^T [b][e8][j] uint4
  {
    const uint4* kc = (const uint4*)kinT + (size_t)b * 16 * 512 + t;
    float a[4] = {0, 0, 0, 0};
    #pragma unroll
    for (int e8 = 0; e8 < 16; ++e8) {
      uint4 w = kc[(size_t)e8 * 512];
      F8(w, 8 * e8, qs, a);
    }
    const float bias = mbuf[b * N + t] ? 0.f : NEG;
    #pragma unroll
    for (int r = 0; r < 4; ++r) p[r][t] = a[r] + bias;
  }
  __syncthreads();

  // C: softmax — wave w handles row w
  if (wid < 4) {
    const int r = wid, lane = t & 63;
    float pv[8];
    float mx = -1e30f;
    #pragma unroll
    for (int k = 0; k < 8; ++k) { pv[k] = p[r][lane + 64 * k]; mx = fmaxf(mx, pv[k]); }
    #pragma unroll
    for (int o = 32; o > 0; o >>= 1) mx = fmaxf(mx, __shfl_xor(mx, o, 64));
    float sum = 0.f;
    #pragma unroll
    for (int k = 0; k < 8; ++k) { pv[k] = __expf(pv[k] - mx); sum += pv[k]; }
    #pragma unroll
    for (int o = 32; o > 0; o >>= 1) sum += __shfl_xor(sum, o, 64);
    #pragma unroll
    for (int k = 0; k < 8; ++k) p[r][lane + 64 * k] = pv[k];
    if (lane == 0) den[r] = sum;
  }
  __syncthreads();

  // D: AV — d=t&127, key-quarter=t>>7; packed V [b][j8][d] uint4
  {
    const int d = t & 127, q4 = t >> 7;
    const uint4* vp = (const uint4*)vinT + ((size_t)b * 64 + q4 * 16) * 128 + d;
    float a[4] = {0, 0, 0, 0};
    #pragma unroll
    for (int j8 = 0; j8 < 16; ++j8) {
      uint4 w = vp[(size_t)j8 * 128];
      F8(w, q4 * 128 + 8 * j8, p, a);
    }
    #pragma unroll
    for (int r = 0; r < 4; ++r) part[q4][r][d] = a[r];
  }
  __syncthreads();
  {
    const int r = t >> 7, d = t & 127;
    os[r][d] = (part[0][r][d] + part[1][r][d] + part[2][r][d] + part[3][r][d]) / den[r];
  }
  __syncthreads();

  // E: WO — d=t&127, e-quarter=t>>7
  {
    const int d = t & 127, eq = t >> 7;
    float a[4] = {0, 0, 0, 0};
    #pragma unroll
    for (int ee = 0; ee < 4; ++ee) {
      const int e8 = eq * 4 + ee;
      uint4 w = WOp[(size_t)e8 * 128 + d];
      F8(w, 8 * e8, os, a);
    }
    #pragma unroll
    for (int r = 0; r < 4; ++r) part[eq][r][d] = a[r];
  }
  __syncthreads();

  // F: residual + LN1 — wave w handles row w
  if (wid < 4) {
    const int r = wid, lane = t & 63;
    float tv[2];
    #pragma unroll
    for (int k = 0; k < 2; ++k) {
      const int d = lane + 64 * k;
      tv[k] = part[0][r][d] + part[1][r][d] + part[2][r][d] + part[3][r][d]
            + bo[d] + xbuf[(size_t)(row0 + r) * D + d];
    }
    float s = tv[0] + tv[1], sq = tv[0] * tv[0] + tv[1] * tv[1];
    #pragma unroll
    for (int o = 32; o > 0; o >>= 1) { s += __shfl_xor(s, o, 64); sq += __shfl_xor(sq, o, 64); }
    const float mean = s * (1.f / 128.f);
    const float var  = sq * (1.f / 128.f) - mean * mean;
    const float rstd = __frsqrt_rn(var + EPS);
    #pragma unroll
    for (int k = 0; k < 2; ++k) {
      const int d = lane + 64 * k;
      xs[r][d] = (tv[k] - mean) * rstd * g1[d] + b1[d];
    }
  }
  __syncthreads();

  // G: FFN1 — thread t owns f=t
  {
    float a[4] = {0, 0, 0, 0};
    #pragma unroll
    for (int e8 = 0; e8 < 16; ++e8) {
      uint4 w = W1p[(size_t)e8 * 512 + t];
      F8(w, 8 * e8, xs, a);
    }
    const float bb = fb1[t];
    #pragma unroll
    for (int r = 0; r < 4; ++r) hs[r][t] = fmaxf(a[r] + bb, 0.f);
  }
  __syncthreads();

  // H: FFN2 — d=t&127, f-quarter=t>>7
  {
    const int d = t & 127, fq = t >> 7;
    float a[4] = {0, 0, 0, 0};
    #pragma unroll
    for (int ff = 0; ff < 16; ++ff) {
      uint4 w = W2p[(size_t)(fq * 16 + ff) * 128 + d];
      F8(w, fq * 128 + 8 * ff, hs, a);
    }
    #pragma unroll
    for (int r = 0; r < 4; ++r) part[fq][r][d] = a[r];
  }
  __syncthreads();

  // I: residual + LN2 — wave w handles row w
  if (wid < 4) {
    const int r = wid, lane = t & 63;
    float tv[2];
    #pragma unroll
    for (int k = 0; k < 2; ++k) {
      const int d = lane + 64 * k;
      tv[k] = part[0][r][d] + part[1][r][d] + part[2][r][d] + part[3][r][d]
            + fb2[d] + xs[r][d];
    }
    float s = tv[0] + tv[1], sq = tv[0] * tv[0] + tv[1] * tv[1];
    #pragma unroll
    for (int o = 32; o > 0; o >>= 1) { s += __shfl_xor(s, o, 64); sq += __shfl_xor(sq, o, 64); }
    const float mean = s * (1.f / 128.f);
    const float var  = sq * (1.f / 128.f) - mean * mean;
    const float rstd = __frsqrt_rn(var + EPS);
    #pragma unroll
    for (int k = 0; k < 2; ++k) {
      const int d = lane + 64 * k;
      const float xn = (tv[k] - mean) * rstd * g2[d] + b2v[d];
      os[r][d] = xn;
      xbuf[(size_t)(row0 + r) * D + d] = xn;
      if (outp) outp[(size_t)(row0 + r) * D + d] = xn;
    }
  }
  __syncthreads();

  // J: QKV for next layer
  if (!last) {
    const int c = t & 127, m = t >> 7;
    if (m < 3) {
      const uint4* Wp = (const uint4*)(Wb + PB_L0 + (l + 1) * PB_LSTR + m * 8192);
      const float* bm = W + ((m == 0) ? OFF_BQ : (m == 1) ? OFF_BK : OFF_BV) + (l + 1) * D;
      float a[4] = {0, 0, 0, 0};
      #pragma unroll
      for (int e8 = 0; e8 < 16; ++e8) {
        uint4 w = Wp[(size_t)e8 * 128 + c];
        F8(w, 8 * e8, os, a);
      }
      const float bv_ = bm[c];
      if (m == 0) {
        #pragma unroll
        for (int r = 0; r < 4; ++r) qout[(size_t)(row0 + r) * D + c] = a[r] + bv_;
      } else if (m == 1) {
        #pragma unroll
        for (int r = 0; r < 4; ++r) part[0][r][c] = a[r] + bv_;
      } else {
        #pragma unroll
        for (int r = 0; r < 4; ++r) part[1][r][c] = a[r] + bv_;
      }
    }
    __syncthreads();
    if (t < 64) {
      const int r = t >> 4, e8 = t & 15;
      const float* ks = part[0][r];
      uint4 w;
      w.x = pk2(ks[8 * e8 + 0], ks[8 * e8 + 1]);
      w.y = pk2(ks[8 * e8 + 2], ks[8 * e8 + 3]);
      w.z = pk2(ks[8 * e8 + 4], ks[8 * e8 + 5]);
      w.w = pk2(ks[8 * e8 + 6], ks[8 * e8 + 7]);
      ((uint4*)koutT)[((size_t)b * 16 + e8) * 512 + (row0 & 511) + r] = w;
    }
    if (t < 128) {
      const int i0 = row0 & 511, j8 = i0 >> 3, h = (i0 >> 2) & 1;
      uint2 w;
      w.x = pk2(part[1][0][t], part[1][1][t]);
      w.y = pk2(part[1][2][t], part[1][3][t]);
      *(uint2*)(voutT + (((size_t)b * 64 + j8) * 128 + t) * 4 + 2 * h) = w;
    }
  }
}

// ---------------------------------------------------------------------------
extern "C" void kernel_launch(void* const* d_in, const int* in_sizes, int n_in,
                              void* d_out, int out_size, void* d_ws, size_t ws_size,
                              hipStream_t stream) {
  // ws layout (4-byte units)
  int*   flags = (int*)d_ws;                 // [0]=isbf16 [1]=mask bytes/elem
  int*   mbuf  = flags + 16;                 // 1024 ints
  float* xbuf  = (float*)d_ws + 1040;        // 1024*128
  float* q0    = xbuf + NROW * D;
  float* q1    = q0 + NROW * D;
  u32*   kT0   = (u32*)(q1 + NROW * D);      // [B][16][512] uint4
  u32*   kT1   = kT0 + 65536;
  u32*   vT0   = kT1 + 65536;                // [B][64][128] uint4
  u32*   vT1   = vT0 + 65536;
  float* W     = (float*)(vT1 + 65536);      // W_TOTAL floats (subset used)
  u32*   Wb    = (u32*)(W + W_TOTAL);        // packed weights

  PrepArgs pa;
  {
    const NEnt nrm[19] = {
      {d_in[1],  OFF_PRE_W,  256}, {d_in[2],  OFF_PRE_B, 128},
      {d_in[4],  OFF_PROJ_B, 128},
      {d_in[6],  OFF_BN_G,   128}, {d_in[7],  OFF_BN_B,  128},
      {d_in[8],  OFF_BN_M,   128}, {d_in[9],  OFF_BN_V,  128},
      {d_in[11], OFF_OUT_B2, 128}, {d_in[12], OFF_PE,  16384},
      {d_in[14], OFF_BQ,     384}, {d_in[16], OFF_BK,    384},
      {d_in[18], OFF_BV,     384}, {d_in[20], OFF_BO,    384},
      {d_in[21], OFF_LN1G,   384}, {d_in[22], OFF_LN1B,  384},
      {d_in[23], OFF_LN2G,   384}, {d_in[24], OFF_LN2B,  384},
      {d_in[26], OFF_FB1,   1536}, {d_in[28], OFF_FB2,   384}};
    for (int i = 0; i < 19; ++i) pa.nrm[i] = nrm[i];

    pa.pk[0] = {d_in[3], d_in[3], 0, 16384, PB_PROJ, 7, 0};
    pa.pk[1] = {d_in[5],  nullptr, 0, 0, PB_OW1, 7, 2048};
    pa.pk[2] = {d_in[10], nullptr, 0, 0, PB_OW2, 7, 4096};
    for (int l = 0; l < 3; ++l) {
      const int lb = PB_L0 + l * PB_LSTR;
      const int cl = 6144 + l * 24576;
      pa.pk[3 + 6 * l + 0] = {d_in[13], nullptr, l * 16384, 0, lb,          7, cl};
      pa.pk[3 + 6 * l + 1] = {d_in[15], nullptr, l * 16384, 0, lb + 8192,   7, cl + 2048};
      pa.pk[3 + 6 * l + 2] = {d_in[17], nullptr, l * 16384, 0, lb + 16384,  7, cl + 4096};
      pa.pk[3 + 6 * l + 3] = {d_in[19], nullptr, l * 16384, 0, lb + PB_WO,  7, cl + 6144};
      pa.pk[3 + 6 * l + 4] = {d_in[25], nullptr, l * 65536, 0, lb + PB_FW1, 9, cl + 8192};
      pa.pk[3 + 6 * l + 5] = {d_in[27], nullptr, l * 65536, 0, lb + PB_FW2, 7, cl + 16384};
    }
  }
  const int* agent_id = (const int*)d_in[30];

  k_prep<<<144, 256, 0, stream>>>(pa, d_in[9], d_in[29], flags, mbuf, W, Wb);
  k_relq<<<NROW / 4, 512, 0, stream>>>(d_in[0], W, Wb, flags, mbuf, agent_id, xbuf,
                                       q0, kT0, vT0);

  float* qs_[2] = {q0, q1};
  u32*   ks_[2] = {kT0, kT1};
  u32*   vs_[2] = {vT0, vT1};
  for (int l = 0; l < 3; ++l) {
    const int cur = l & 1, nxt = cur ^ 1;
    const int last = (l == 2);
    k_layer<<<NROW / 4, 512, 0, stream>>>(
        qs_[cur], ks_[cur], vs_[cur],
        W, Wb, l, last,
        qs_[nxt], ks_[nxt], vs_[nxt],
        mbuf, xbuf, last ? (float*)d_out : (float*)nullptr);
  }
}

// Round 8
// 77.320 us; speedup vs baseline: 4.3650x; 1.1599x over previous
//
#include <hip/hip_runtime.h>
#include <hip/hip_bf16.h>

typedef unsigned short u16;
typedef unsigned int u32;
typedef unsigned char u8;
typedef __attribute__((ext_vector_type(8))) short bf16x8;
typedef __attribute__((ext_vector_type(4))) float f32x4;

#define DEV __device__ __forceinline__

DEV float bf2f(u16 u) { union { u32 i; float f; } c; c.i = ((u32)u) << 16; return c.f; }
DEV u16 f2bf(float f) {  // round-to-nearest-even
  union { float f; u32 i; } c; c.f = f;
  u32 r = c.i + 0x7FFFu + ((c.i >> 16) & 1u);
  return (u16)(r >> 16);
}
DEV u32 pk2(float lo, float hi) { return (u32)f2bf(lo) | ((u32)f2bf(hi) << 16); }
DEV float rdsrc(const void* p, int e, int isb) {
  return isb ? bf2f(((const u16*)p)[e]) : ((const float*)p)[e];
}
DEV bf16x8 as_bf(uint4 v) { union { uint4 u; bf16x8 h; } c; c.u = v; return c.h; }

static constexpr int B = 2, N = 512, D = 128, F = 512;
static constexpr int NROW = B * N;  // 1024
static constexpr float EPS = 1e-5f;
static constexpr float NEG = -1e9f;
static constexpr float SCALE = 0.08838834764831845f;  // 1/sqrt(128)

// ---- fp32 small-weight region offsets ------------------------------------
#define OFF_PRE_W   0
#define OFF_PRE_B   256
#define OFF_PROJ_B  33152
#define OFF_BN_G    49664
#define OFF_BN_B    49792
#define OFF_BN_M    49920
#define OFF_BN_V    50048
#define OFF_OUT_B2  66560
#define OFF_PE      66688
#define OFF_BQ      132224
#define OFF_BK      181760
#define OFF_BV      231296
#define OFF_BO      280832
#define OFF_LN1G    281216
#define OFF_LN1B    281600
#define OFF_LN2G    281984
#define OFF_LN2B    282368
#define OFF_FB1     479360
#define OFF_FB2     677504
#define W_TOTAL     677888

// ---- packed-bf16 weight region (u32 units; [e8][col] uint4 of 8 K-elems) --
static constexpr int PB_PROJ = 0;
static constexpr int PB_OW1  = 8192;
static constexpr int PB_OW2  = 16384;
static constexpr int PB_L0   = 24576;
static constexpr int PB_LSTR = 98304;
static constexpr int PB_WO   = 24576;
static constexpr int PB_FW1  = 32768;
static constexpr int PB_FW2  = 65536;
static constexpr int PTOT    = 79872;   // total uint4 pack entries

struct NEnt { const void* s; int off, n; };
struct PEnt { const void* s1; const void* s2; int o1, o2, dst, lgn, cum; };
struct PrepArgs { NEnt nrm[19]; PEnt pk[21]; };

// ---------------------------------------------------------------------------
// MFMA helpers: A = 4 real rows (rows 4..15 zero) packed [e8][16] uint4 in
// LDS; B = [e8][ncol] uint4 in global. D rows 0..3 land in lanes 0..15,
// regs 0..3 (verified gfx950 C/D mapping: col=lane&15, row=(lane>>4)*4+reg).
// ---------------------------------------------------------------------------
template<int KT>
DEV f32x4 mmaK(const uint4* __restrict__ aPk, const uint4* __restrict__ Bp,
               int ncol, int col, int lane) {
  f32x4 acc = {0.f, 0.f, 0.f, 0.f};
  const int sub = lane >> 4;
  #pragma unroll
  for (int kt = 0; kt < KT; ++kt) {
    const int e8 = kt * 4 + sub;
    acc = __builtin_amdgcn_mfma_f32_16x16x32_bf16(
        as_bf(aPk[e8 * 16 + (lane & 15)]),
        as_bf(Bp[(size_t)e8 * ncol + col]),
        acc, 0, 0, 0);
  }
  return acc;
}

DEV void packA(const float* __restrict__ src, int ld, int K,
               uint4* __restrict__ aPk, int t) {
  const int n = (K >> 3) * 4;            // (K/8 e8-chunks) x 4 rows
  for (int i = t; i < n; i += 512) {
    const int e8 = i >> 2, r = i & 3;
    const float* s = src + r * ld + e8 * 8;
    uint4 w;
    w.x = pk2(s[0], s[1]); w.y = pk2(s[2], s[3]);
    w.z = pk2(s[4], s[5]); w.w = pk2(s[6], s[7]);
    aPk[e8 * 16 + r] = w;
  }
}

// ---------------------------------------------------------------------------
// k_prep: (a) blocks 0..15 norm small tensors; (b) 16..142 build packed
// weights; (c) 143 normalizes mask. Each block self-detects dtype via bn_v.
// ---------------------------------------------------------------------------
__global__ __launch_bounds__(256) void k_prep(PrepArgs pa,
    const void* __restrict__ bnv, const void* __restrict__ maskp,
    int* __restrict__ flags, int* __restrict__ mbuf,
    float* __restrict__ W, u32* __restrict__ Wb)
{
  const int t = threadIdx.x, bid = blockIdx.x;
  __shared__ int s_nb, s_m4, s_m2;
  if (t == 0) { s_nb = 0; s_m4 = 0; s_m2 = 0; }
  __syncthreads();
  if (t < 64) {
    const u32 w = ((const u32*)bnv)[t];
    if (((w >> 8) & 0xFFu) != 0x3Fu || ((w >> 24) & 0xFFu) != 0x3Fu)
      atomicOr(&s_nb, 1);
  }
  __syncthreads();
  const int isb = s_nb ? 0 : 1;

  if (bid < 16) {
    for (int ten = 0; ten < 19; ++ten) {
      const NEnt E = pa.nrm[ten];
      for (int e = bid * 256 + t; e < E.n; e += 16 * 256)
        W[E.off + e] = rdsrc(E.s, e, isb);
    }
  } else if (bid < 143) {
    for (int g = (bid - 16) * 256 + t; g < PTOT; g += 127 * 256) {
      int ei = 0;
      #pragma unroll
      for (int k = 1; k < 21; ++k) if (g >= pa.pk[k].cum) ei = k;
      const PEnt E = pa.pk[ei];
      const int li = g - E.cum;
      const int e8 = li >> E.lgn, c = li & ((1 << E.lgn) - 1);
      float f[8];
      #pragma unroll
      for (int i = 0; i < 8; ++i) {
        const int si = ((e8 * 8 + i) << E.lgn) + c;
        f[i] = rdsrc(E.s1, E.o1 + si, isb);
        if (E.s2) f[i] += rdsrc(E.s2, E.o2 + si, isb);
      }
      uint4 w;
      w.x = pk2(f[0], f[1]); w.y = pk2(f[2], f[3]);
      w.z = pk2(f[4], f[5]); w.w = pk2(f[6], f[7]);
      ((uint4*)(Wb + E.dst))[li] = w;
    }
  } else {
    {
      const u32 w = ((const u32*)maskp)[t];
      if (!(w == 0u || w == 1u || w == 0x3F800000u)) atomicOr(&s_m4, 1);
      if (!(w == 0u || w == 1u || w == 0x10000u || w == 0x10001u ||
            w == 0x3F80u || w == 0x3F800000u || w == 0x3F803F80u)) atomicOr(&s_m2, 1);
    }
    __syncthreads();
    const int mode = (!s_m4) ? 4 : ((!s_m2) ? 2 : 1);
    if (t == 0) { flags[0] = isb; flags[1] = mode; }
    #pragma unroll
    for (int k = 0; k < 4; ++k) {
      const int e = k * 256 + t;
      int v;
      if (mode == 4)      v = (((const u32*)maskp)[e] != 0u);
      else if (mode == 2) v = (((const u16*)maskp)[e] != 0);
      else                v = (((const u8*)maskp)[e]  != 0);
      mbuf[e] = v;
    }
  }
}

// ---------------------------------------------------------------------------
// k_relq: collapsed pairwise chain + out-MLP + PE + QKV(layer 0).
// 4 rows/block, 256 blocks, 512 threads; GEMM phases on MFMA.
// ---------------------------------------------------------------------------
__global__ __launch_bounds__(512) void k_relq(
    const void* __restrict__ relv, const float* __restrict__ W,
    const u32* __restrict__ Wb,
    const int* __restrict__ flags, const int* __restrict__ mbuf,
    const int* __restrict__ agent_id, float* __restrict__ xbuf,
    float* __restrict__ qb, u32* __restrict__ kbT, u32* __restrict__ vbT)
{
  const int t = threadIdx.x;            // 0..511
  const int row0 = blockIdx.x * 4;
  const int b = row0 >> 9;
  const int wid = t >> 6;
  const int lane = t & 63;

  __shared__ float pl[4][D], zl[4][D], rl[4][D], os[4][D];
  __shared__ float pA[4][D], pB[4][D];
  __shared__ uint4 aPk[1024];
  __shared__ float wred[8][9];
  __shared__ float sT0[4], sT1[4], sMt;

  // --- P1: masked sums over j of rel channels; Mtot (+ aPk zero-init) ---
  float s0[4] = {0, 0, 0, 0}, s1[4] = {0, 0, 0, 0}, cnt;
  {
    const int j = t;
    const float m = (float)mbuf[b * N + j];
    cnt = m;
    if (flags[0]) {
      const u32* rel2 = (const u32*)relv;
      #pragma unroll
      for (int r = 0; r < 4; ++r) {
        const u32 u = rel2[(size_t)(row0 + r) * N + j];
        s0[r] += m * bf2f((u16)(u & 0xFFFFu));
        s1[r] += m * bf2f((u16)(u >> 16));
      }
    } else {
      const float2* relf = (const float2*)relv;
      #pragma unroll
      for (int r = 0; r < 4; ++r) {
        const float2 u = relf[(size_t)(row0 + r) * N + j];
        s0[r] += m * u.x; s1[r] += m * u.y;
      }
    }
  }
  {
    const uint4 z = {0u, 0u, 0u, 0u};
    aPk[t] = z; aPk[t + 512] = z;
  }
  #pragma unroll
  for (int o = 32; o > 0; o >>= 1) {
    #pragma unroll
    for (int r = 0; r < 4; ++r) {
      s0[r] += __shfl_xor(s0[r], o, 64);
      s1[r] += __shfl_xor(s1[r], o, 64);
    }
    cnt += __shfl_xor(cnt, o, 64);
  }
  if ((t & 63) == 0) {
    #pragma unroll
    for (int r = 0; r < 4; ++r) { wred[wid][r] = s0[r]; wred[wid][4 + r] = s1[r]; }
    wred[wid][8] = cnt;
  }
  __syncthreads();
  if (t < 4) {
    float a0 = 0, a1 = 0;
    #pragma unroll
    for (int w = 0; w < 8; ++w) { a0 += wred[w][t]; a1 += wred[w][4 + t]; }
    sT0[t] = a0; sT1[t] = a1;
  }
  if (t == 8) {
    float c = 0;
    #pragma unroll
    for (int w = 0; w < 8; ++w) c += wred[w][8];
    sMt = c;
  }
  __syncthreads();

  // --- P2: pooled ---
  {
    const int r = t >> 7, c = t & 127;
    const int mi = mbuf[row0 + r];
    pl[r][c] = mi ? (sT0[r] * W[OFF_PRE_W + c] + sT1[r] * W[OFF_PRE_W + D + c]) / sMt
                    + W[OFF_PRE_B + c]
                  : 0.f;
  }
  __syncthreads();

  // --- P3: pooled @ (P1+P2) -> pA ---
  packA(&pl[0][0], D, D, aPk, t);
  __syncthreads();
  {
    const int col = wid * 16 + (lane & 15);
    f32x4 acc = mmaK<4>(aPk, (const uint4*)(Wb + PB_PROJ), 128, col, lane);
    if (lane < 16) {
      #pragma unroll
      for (int g = 0; g < 4; ++g) pA[g][col] = acc[g];
    }
  }
  __syncthreads();
  {
    const int r = t >> 7, d = t & 127;
    zl[r][d] = mbuf[row0 + r] ? pA[r][d] + W[OFF_PROJ_B + d] : 0.f;
  }
  __syncthreads();

  // --- P4: z @ out_w1; bn; relu ---
  packA(&zl[0][0], D, D, aPk, t);
  __syncthreads();
  {
    const int col = wid * 16 + (lane & 15);
    f32x4 acc = mmaK<4>(aPk, (const uint4*)(Wb + PB_OW1), 128, col, lane);
    if (lane < 16) {
      #pragma unroll
      for (int g = 0; g < 4; ++g) pA[g][col] = acc[g];
    }
  }
  __syncthreads();
  {
    const int r = t >> 7, d = t & 127;
    const float hb = (pA[r][d] - W[OFF_BN_M + d]) * __frsqrt_rn(W[OFF_BN_V + d] + EPS)
                     * W[OFF_BN_G + d] + W[OFF_BN_B + d];
    rl[r][d] = fmaxf(hb, 0.f);
  }
  __syncthreads();

  // --- P5: relu_h @ out_w2 + out_b2 + pe ---
  packA(&rl[0][0], D, D, aPk, t);
  __syncthreads();
  {
    const int col = wid * 16 + (lane & 15);
    f32x4 acc = mmaK<4>(aPk, (const uint4*)(Wb + PB_OW2), 128, col, lane);
    if (lane < 16) {
      #pragma unroll
      for (int g = 0; g < 4; ++g) pA[g][col] = acc[g];
    }
  }
  __syncthreads();
  {
    const int r = t >> 7, d = t & 127;
    const int aid = agent_id[row0 + r];
    const float x0 = pA[r][d] + W[OFF_OUT_B2 + d] + W[OFF_PE + aid * D + d];
    os[r][d] = x0;
    xbuf[(size_t)(row0 + r) * D + d] = x0;
  }
  __syncthreads();

  // --- P6: QKV layer 0 ---
  packA(&os[0][0], D, D, aPk, t);
  __syncthreads();
  {
    const int col = wid * 16 + (lane & 15);
    #pragma unroll
    for (int m = 0; m < 3; ++m) {
      f32x4 acc = mmaK<4>(aPk, (const uint4*)(Wb + PB_L0 + m * 8192), 128, col, lane);
      if (lane < 16) {
        const float bb = W[(m == 0 ? OFF_BQ : m == 1 ? OFF_BK : OFF_BV) + col];
        if (m == 0) {
          #pragma unroll
          for (int g = 0; g < 4; ++g) qb[(size_t)(row0 + g) * D + col] = acc[g] + bb;
        } else if (m == 1) {
          #pragma unroll
          for (int g = 0; g < 4; ++g) pA[g][col] = acc[g] + bb;
        } else {
          #pragma unroll
          for (int g = 0; g < 4; ++g) pB[g][col] = acc[g] + bb;
        }
      }
    }
  }
  __syncthreads();
  if (t < 64) {   // packed K^T write: [b][e8][j] uint4
    const int r = t >> 4, e8 = t & 15;
    const float* ks = pA[r];
    uint4 w;
    w.x = pk2(ks[8 * e8 + 0], ks[8 * e8 + 1]);
    w.y = pk2(ks[8 * e8 + 2], ks[8 * e8 + 3]);
    w.z = pk2(ks[8 * e8 + 4], ks[8 * e8 + 5]);
    w.w = pk2(ks[8 * e8 + 6], ks[8 * e8 + 7]);
    ((uint4*)kbT)[((size_t)b * 16 + e8) * 512 + (row0 & 511) + r] = w;
  }
  if (t < 128) {  // packed V write: [b][j8][d] uint4 (half per block)
    const int i0 = row0 & 511, j8 = i0 >> 3, h = (i0 >> 2) & 1;
    uint2 w;
    w.x = pk2(pB[0][t], pB[1][t]);
    w.y = pk2(pB[2][t], pB[3][t]);
    *(uint2*)(vbT + (((size_t)b * 64 + j8) * 128 + t) * 4 + 2 * h) = w;
  }
}

// ---------------------------------------------------------------------------
// k_layer: fused attn + LN1 + FFN + LN2 [+ QKV(l+1)] for 4 rows/block.
// 256 blocks, 512 threads; all GEMM phases on MFMA (M=16, rows 0..3 live).
// ---------------------------------------------------------------------------
__global__ __launch_bounds__(512) void k_layer(
    const float* __restrict__ qin, const u32* __restrict__ kinT, const u32* __restrict__ vinT,
    const float* __restrict__ W, const u32* __restrict__ Wb, const int l, const int last,
    float* __restrict__ qout, u32* __restrict__ koutT, u32* __restrict__ voutT,
    const int* __restrict__ mbuf, float* __restrict__ xbuf, float* __restrict__ outp)
{
  const int t = threadIdx.x;            // 0..511
  const int row0 = blockIdx.x * 4;
  const int b = row0 >> 9;
  const int wid = t >> 6;
  const int lane = t & 63;

  const uint4* WOp = (const uint4*)(Wb + PB_L0 + l * PB_LSTR + PB_WO);
  const uint4* W1p = (const uint4*)(Wb + PB_L0 + l * PB_LSTR + PB_FW1);
  const uint4* W2p = (const uint4*)(Wb + PB_L0 + l * PB_LSTR + PB_FW2);
  const float* bo  = W + OFF_BO  + l * D;
  const float* g1  = W + OFF_LN1G + l * D;
  const float* b1  = W + OFF_LN1B + l * D;
  const float* fb1 = W + OFF_FB1 + l * F;
  const float* fb2 = W + OFF_FB2 + l * D;
  const float* g2  = W + OFF_LN2G + l * D;
  const float* b2v = W + OFF_LN2B + l * D;

  __shared__ float qs[4][D];
  __shared__ float p[4][N];
  __shared__ float hs[4][F];
  __shared__ float os[4][D];
  __shared__ float xs[4][D];
  __shared__ float pA[4][D], pB[4][D];
  __shared__ uint4 aPk[1024];
  __shared__ float den[4];

  // A: load Q rows pre-scaled + zero aPk
  {
    const int r = t >> 7, d = t & 127;
    qs[r][d] = qin[(size_t)(row0 + r) * D + d] * SCALE;
    const uint4 z = {0u, 0u, 0u, 0u};
    aPk[t] = z; aPk[t + 512] = z;
  }
  __syncthreads();

  // B: scores via MFMA — p[r][j] = q.k + bias
  packA(&qs[0][0], D, D, aPk, t);
  __syncthreads();
  {
    const uint4* Kp = (const uint4*)kinT + (size_t)b * 16 * 512;
    #pragma unroll
    for (int i = 0; i < 4; ++i) {
      const int col = (wid * 4 + i) * 16 + (lane & 15);
      f32x4 acc = mmaK<4>(aPk, Kp, 512, col, lane);
      if (lane < 16) {
        const float bias = mbuf[b * N + col] ? 0.f : NEG;
        #pragma unroll
        for (int g = 0; g < 4; ++g) p[g][col] = acc[g] + bias;
      }
    }
  }
  __syncthreads();

  // C: softmax — wave w handles row w
  if (wid < 4) {
    const int r = wid;
    float pv[8];
    float mx = -1e30f;
    #pragma unroll
    for (int k = 0; k < 8; ++k) { pv[k] = p[r][lane + 64 * k]; mx = fmaxf(mx, pv[k]); }
    #pragma unroll
    for (int o = 32; o > 0; o >>= 1) mx = fmaxf(mx, __shfl_xor(mx, o, 64));
    float sum = 0.f;
    #pragma unroll
    for (int k = 0; k < 8; ++k) { pv[k] = __expf(pv[k] - mx); sum += pv[k]; }
    #pragma unroll
    for (int o = 32; o > 0; o >>= 1) sum += __shfl_xor(sum, o, 64);
    #pragma unroll
    for (int k = 0; k < 8; ++k) p[r][lane + 64 * k] = pv[k];
    if (lane == 0) den[r] = sum;
  }
  __syncthreads();

  // D: AV via MFMA (K=512) — os = (p @ V)/den
  packA(&p[0][0], N, N, aPk, t);
  __syncthreads();
  {
    const int col = wid * 16 + (lane & 15);
    const uint4* Vp = (const uint4*)vinT + (size_t)b * 64 * 128;
    f32x4 acc = mmaK<16>(aPk, Vp, 128, col, lane);
    if (lane < 16) {
      #pragma unroll
      for (int g = 0; g < 4; ++g) os[g][col] = acc[g] / den[g];
    }
  }
  __syncthreads();

  // E: WO via MFMA -> pA
  packA(&os[0][0], D, D, aPk, t);
  __syncthreads();
  {
    const int col = wid * 16 + (lane & 15);
    f32x4 acc = mmaK<4>(aPk, WOp, 128, col, lane);
    if (lane < 16) {
      #pragma unroll
      for (int g = 0; g < 4; ++g) pA[g][col] = acc[g];
    }
  }
  __syncthreads();

  // F: residual + LN1 — wave w handles row w
  if (wid < 4) {
    const int r = wid;
    float tv[2];
    #pragma unroll
    for (int k = 0; k < 2; ++k) {
      const int d = lane + 64 * k;
      tv[k] = pA[r][d] + bo[d] + xbuf[(size_t)(row0 + r) * D + d];
    }
    float s = tv[0] + tv[1], sq = tv[0] * tv[0] + tv[1] * tv[1];
    #pragma unroll
    for (int o = 32; o > 0; o >>= 1) { s += __shfl_xor(s, o, 64); sq += __shfl_xor(sq, o, 64); }
    const float mean = s * (1.f / 128.f);
    const float var  = sq * (1.f / 128.f) - mean * mean;
    const float rstd = __frsqrt_rn(var + EPS);
    #pragma unroll
    for (int k = 0; k < 2; ++k) {
      const int d = lane + 64 * k;
      xs[r][d] = (tv[k] - mean) * rstd * g1[d] + b1[d];
    }
  }
  __syncthreads();

  // G: FFN1 via MFMA — hs = relu(xs @ W1 + fb1)
  packA(&xs[0][0], D, D, aPk, t);
  __syncthreads();
  {
    #pragma unroll
    for (int i = 0; i < 4; ++i) {
      const int col = (wid * 4 + i) * 16 + (lane & 15);
      f32x4 acc = mmaK<4>(aPk, W1p, 512, col, lane);
      if (lane < 16) {
        const float bb = fb1[col];
        #pragma unroll
        for (int g = 0; g < 4; ++g) hs[g][col] = fmaxf(acc[g] + bb, 0.f);
      }
    }
  }
  __syncthreads();

  // H: FFN2 via MFMA (K=512) -> pA
  packA(&hs[0][0], F, F, aPk, t);
  __syncthreads();
  {
    const int col = wid * 16 + (lane & 15);
    f32x4 acc = mmaK<16>(aPk, W2p, 128, col, lane);
    if (lane < 16) {
      #pragma unroll
      for (int g = 0; g < 4; ++g) pA[g][col] = acc[g];
    }
  }
  __syncthreads();

  // I: residual + LN2 — wave w handles row w; write os/xbuf (+outp)
  if (wid < 4) {
    const int r = wid;
    float tv[2];
    #pragma unroll
    for (int k = 0; k < 2; ++k) {
      const int d = lane + 64 * k;
      tv[k] = pA[r][d] + fb2[d] + xs[r][d];
    }
    float s = tv[0] + tv[1], sq = tv[0] * tv[0] + tv[1] * tv[1];
    #pragma unroll
    for (int o = 32; o > 0; o >>= 1) { s += __shfl_xor(s, o, 64); sq += __shfl_xor(sq, o, 64); }
    const float mean = s * (1.f / 128.f);
    const float var  = sq * (1.f / 128.f) - mean * mean;
    const float rstd = __frsqrt_rn(var + EPS);
    #pragma unroll
    for (int k = 0; k < 2; ++k) {
      const int d = lane + 64 * k;
      const float xn = (tv[k] - mean) * rstd * g2[d] + b2v[d];
      os[r][d] = xn;
      xbuf[(size_t)(row0 + r) * D + d] = xn;
      if (outp) outp[(size_t)(row0 + r) * D + d] = xn;
    }
  }
  __syncthreads();

  // J: QKV for next layer via MFMA
  if (!last) {
    packA(&os[0][0], D, D, aPk, t);
    __syncthreads();
    {
      const int col = wid * 16 + (lane & 15);
      #pragma unroll
      for (int m = 0; m < 3; ++m) {
        const uint4* Bp = (const uint4*)(Wb + PB_L0 + (l + 1) * PB_LSTR + m * 8192);
        f32x4 acc = mmaK<4>(aPk, Bp, 128, col, lane);
        if (lane < 16) {
          const float bb = W[(m == 0 ? OFF_BQ : m == 1 ? OFF_BK : OFF_BV) + (l + 1) * D + col];
          if (m == 0) {
            #pragma unroll
            for (int g = 0; g < 4; ++g) qout[(size_t)(row0 + g) * D + col] = acc[g] + bb;
          } else if (m == 1) {
            #pragma unroll
            for (int g = 0; g < 4; ++g) pA[g][col] = acc[g] + bb;
          } else {
            #pragma unroll
            for (int g = 0; g < 4; ++g) pB[g][col] = acc[g] + bb;
          }
        }
      }
    }
    __syncthreads();
    if (t < 64) {
      const int r = t >> 4, e8 = t & 15;
      const float* ks = pA[r];
      uint4 w;
      w.x = pk2(ks[8 * e8 + 0], ks[8 * e8 + 1]);
      w.y = pk2(ks[8 * e8 + 2], ks[8 * e8 + 3]);
      w.z = pk2(ks[8 * e8 + 4], ks[8 * e8 + 5]);
      w.w = pk2(ks[8 * e8 + 6], ks[8 * e8 + 7]);
      ((uint4*)koutT)[((size_t)b * 16 + e8) * 512 + (row0 & 511) + r] = w;
    }
    if (t < 128) {
      const int i0 = row0 & 511, j8 = i0 >> 3, h = (i0 >> 2) & 1;
      uint2 w;
      w.x = pk2(pB[0][t], pB[1][t]);
      w.y = pk2(pB[2][t], pB[3][t]);
      *(uint2*)(voutT + (((size_t)b * 64 + j8) * 128 + t) * 4 + 2 * h) = w;
    }
  }
}

// ---------------------------------------------------------------------------
extern "C" void kernel_launch(void* const* d_in, const int* in_sizes, int n_in,
                              void* d_out, int out_size, void* d_ws, size_t ws_size,
                              hipStream_t stream) {
  // ws layout (4-byte units)
  int*   flags = (int*)d_ws;
  int*   mbuf  = flags + 16;
  float* xbuf  = (float*)d_ws + 1040;
  float* q0    = xbuf + NROW * D;
  float* q1    = q0 + NROW * D;
  u32*   kT0   = (u32*)(q1 + NROW * D);      // [B][16][512] uint4
  u32*   kT1   = kT0 + 65536;
  u32*   vT0   = kT1 + 65536;                // [B][64][128] uint4
  u32*   vT1   = vT0 + 65536;
  float* W     = (float*)(vT1 + 65536);
  u32*   Wb    = (u32*)(W + W_TOTAL);

  PrepArgs pa;
  {
    const NEnt nrm[19] = {
      {d_in[1],  OFF_PRE_W,  256}, {d_in[2],  OFF_PRE_B, 128},
      {d_in[4],  OFF_PROJ_B, 128},
      {d_in[6],  OFF_BN_G,   128}, {d_in[7],  OFF_BN_B,  128},
      {d_in[8],  OFF_BN_M,   128}, {d_in[9],  OFF_BN_V,  128},
      {d_in[11], OFF_OUT_B2, 128}, {d_in[12], OFF_PE,  16384},
      {d_in[14], OFF_BQ,     384}, {d_in[16], OFF_BK,    384},
      {d_in[18], OFF_BV,     384}, {d_in[20], OFF_BO,    384},
      {d_in[21], OFF_LN1G,   384}, {d_in[22], OFF_LN1B,  384},
      {d_in[23], OFF_LN2G,   384}, {d_in[24], OFF_LN2B,  384},
      {d_in[26], OFF_FB1,   1536}, {d_in[28], OFF_FB2,   384}};
    for (int i = 0; i < 19; ++i) pa.nrm[i] = nrm[i];

    pa.pk[0] = {d_in[3], d_in[3], 0, 16384, PB_PROJ, 7, 0};
    pa.pk[1] = {d_in[5],  nullptr, 0, 0, PB_OW1, 7, 2048};
    pa.pk[2] = {d_in[10], nullptr, 0, 0, PB_OW2, 7, 4096};
    for (int l = 0; l < 3; ++l) {
      const int lb = PB_L0 + l * PB_LSTR;
      const int cl = 6144 + l * 24576;
      pa.pk[3 + 6 * l + 0] = {d_in[13], nullptr, l * 16384, 0, lb,          7, cl};
      pa.pk[3 + 6 * l + 1] = {d_in[15], nullptr, l * 16384, 0, lb + 8192,   7, cl + 2048};
      pa.pk[3 + 6 * l + 2] = {d_in[17], nullptr, l * 16384, 0, lb + 16384,  7, cl + 4096};
      pa.pk[3 + 6 * l + 3] = {d_in[19], nullptr, l * 16384, 0, lb + PB_WO,  7, cl + 6144};
      pa.pk[3 + 6 * l + 4] = {d_in[25], nullptr, l * 65536, 0, lb + PB_FW1, 9, cl + 8192};
      pa.pk[3 + 6 * l + 5] = {d_in[27], nullptr, l * 65536, 0, lb + PB_FW2, 7, cl + 16384};
    }
  }
  const int* agent_id = (const int*)d_in[30];

  k_prep<<<144, 256, 0, stream>>>(pa, d_in[9], d_in[29], flags, mbuf, W, Wb);
  k_relq<<<NROW / 4, 512, 0, stream>>>(d_in[0], W, Wb, flags, mbuf, agent_id, xbuf,
                                       q0, kT0, vT0);

  float* qs_[2] = {q0, q1};
  u32*   ks_[2] = {kT0, kT1};
  u32*   vs_[2] = {vT0, vT1};
  for (int l = 0; l < 3; ++l) {
    const int cur = l & 1, nxt = cur ^ 1;
    const int last = (l == 2);
    k_layer<<<NROW / 4, 512, 0, stream>>>(
        qs_[cur], ks_[cur], vs_[cur],
        W, Wb, l, last,
        qs_[nxt], ks_[nxt], vs_[nxt],
        mbuf, xbuf, last ? (float*)d_out : (float*)nullptr);
  }
}